// Round 4
// baseline (9999.584 us; speedup 1.0000x reference)
//
#include <hip/hip_runtime.h>
#include <math.h>

constexpr int cB = 128;
constexpr int cC = 9;
constexpr int cT = 512;
constexpr int cM = 64;
constexpr int cDOB = 40;
constexpr int cDM = 360;
constexpr int cD = 376;       // d_model + d_pe
constexpr int cDH = 94;
constexpr int cNHID = 720;
constexpr float cEPS = 1e-5f;
constexpr float cPI = 3.14159265358979323846f;

// ---------------- chirp kernel g = ifft(chirp) ----------------
__global__ void k_chirp(float2* __restrict__ g) {
  int d = threadIdx.x;  // 512 threads
  float re = 0.f, im = 0.f;
  for (int k = 0; k < cT; ++k) {
    int q = (k * k) & 2047;   // chirp phase: pi*k^2/1024, period 2048
    int p = (k * d) & 511;    // ifft twiddle: 2pi*k*d/512, period 512
    float th = cPI * ((float)p * (1.0f / 256.0f) - (float)q * (1.0f / 1024.0f));
    float s, c;
    sincosf(th, &s, &c);
    re += c; im += s;
  }
  g[d] = make_float2(re * (1.0f / 512.0f), im * (1.0f / 512.0f));
}

// ---------------- spectral branch: frft modes, out_ft (REAL PART ONLY), EF ----------------
// Harness stores the complex64 output as one float32 per complex element
// (out_size counts complex elems; numpy astype(float32) keeps the real part).
__global__ __launch_bounds__(512) void k_spectral(
    const float* __restrict__ x, const float* __restrict__ w1r,
    const float* __restrict__ w1i, const float2* __restrict__ g,
    float* __restrict__ outft, float* __restrict__ EF) {
  __shared__ float xc[cC][cT];
  __shared__ float2 gs[cT];
  __shared__ float2 xfr[cC][cM];
  int b = blockIdx.x, tid = threadIdx.x;
  for (int i = tid; i < cC * cT; i += 512)
    xc[i / cT][i % cT] = cosf(x[(size_t)b * cC * cT + i]);
  for (int i = tid; i < cT; i += 512) gs[i] = g[i];
  __syncthreads();
  for (int idx = tid; idx < cC * cM; idx += 512) {
    int c = idx / cM, m = idx % cM;
    float re = 0.f, im = 0.f;
    for (int t = 0; t < cT; ++t) {
      float xv = xc[c][t];
      float2 gv = gs[(m - t) & (cT - 1)];
      re += xv * gv.x; im += xv * gv.y;
    }
    xfr[c][m] = make_float2(re, im);
  }
  __syncthreads();
  for (int idx = tid; idx < cC * cM; idx += 512) {
    int o = idx / cM, m = idx % cM;
    float re = 0.f, im = 0.f;
    #pragma unroll
    for (int i = 0; i < cC; ++i) {
      float2 xv = xfr[i][m];
      float wr = w1r[(i * cC + o) * cM + m];
      float wi = w1i[(i * cC + o) * cM + m];
      re += xv.x * wr - xv.y * wi;
      im += xv.x * wi + xv.y * wr;
    }
    outft[(size_t)(b * cC + o) * cT + m] = re;   // real part only
    EF[(b * cC + o) * (2 * cM) + m] = sqrtf(re * re + im * im);
    EF[(b * cC + o) * (2 * cM) + cM + m] = atan2f(im, re);
  }
  for (int idx = tid; idx < cC * (cT - cM); idx += 512) {
    int o = idx / (cT - cM);
    int r = idx % (cT - cM);
    outft[(size_t)(b * cC + o) * cT + cM + r] = 0.f;
  }
}

// ---------------- conv1d C->1 over feature axis ----------------
__global__ void k_convef(const float* __restrict__ EF, const float* __restrict__ cw,
                         float* __restrict__ efp) {
  int i = blockIdx.x * blockDim.x + threadIdx.x;
  if (i >= cB * 2 * cM) return;
  int b = i / (2 * cM), f = i % (2 * cM);
  float acc = 0.f;
  #pragma unroll
  for (int c = 0; c < cC; ++c) {
    const float* row = EF + (b * cC + c) * (2 * cM);
    if (f > 0) acc += row[f - 1] * cw[c * 3 + 0];
    acc += row[f] * cw[c * 3 + 1];
    if (f < 2 * cM - 1) acc += row[f + 1] * cw[c * 3 + 2];
  }
  efp[i] = acc;
}

// ---------------- batchnorm over batch dim (B=128 = blockDim) ----------------
__global__ __launch_bounds__(128) void k_bn(const float* __restrict__ in,
    const float* __restrict__ gam, const float* __restrict__ bet,
    float* __restrict__ dst, int F, int stride, int off, int reluAfter) {
  __shared__ float red[128];
  int f = blockIdx.x, bt = threadIdx.x;
  float v = in[(size_t)bt * F + f];
  red[bt] = v; __syncthreads();
  for (int s = 64; s > 0; s >>= 1) { if (bt < s) red[bt] += red[bt + s]; __syncthreads(); }
  float mean = red[0] * (1.0f / 128.0f);
  __syncthreads();
  float d = v - mean;
  red[bt] = d * d; __syncthreads();
  for (int s = 64; s > 0; s >>= 1) { if (bt < s) red[bt] += red[bt + s]; __syncthreads(); }
  float var = red[0] * (1.0f / 128.0f);
  float o = d * rsqrtf(var + cEPS) * gam[f] + bet[f];
  if (reluAfter) o = fmaxf(o, 0.f);
  dst[(size_t)bt * stride + off + f] = o;
}

// ---------------- raindrop branch -> z0 [Bc,T,D] ----------------
__global__ __launch_bounds__(256) void k_raindrop(const float* __restrict__ x,
    const float* __restrict__ Ru, const float* __restrict__ Wg1,
    const float* __restrict__ Wg2, float* __restrict__ Z, int bStart) {
  __shared__ float w1s[cDOB * cDOB], w2s[cDOB * cDOB], rus[cDM], tss[8];
  __shared__ float vsh[256][cDOB];
  int tid = threadIdx.x;
  for (int i = tid; i < cDOB * cDOB; i += 256) { w1s[i] = Wg1[i]; w2s[i] = Wg2[i]; }
  for (int i = tid; i < cDM; i += 256) rus[i] = Ru[i];
  if (tid < 8) tss[tid] = powf(100.0f, (float)tid * (1.0f / 7.0f));
  __syncthreads();
  int token0 = blockIdx.x * 256;
  int token = token0 + tid;
  int bl = token / cT, t = token % cT;
  int bg = bStart + bl;
  float s[cDOB];
  #pragma unroll
  for (int d = 0; d < cDOB; ++d) s[d] = 0.f;
  #pragma unroll
  for (int c = 0; c < cC; ++c) {
    float xv = x[((size_t)bg * cC + c) * cT + t];
    #pragma unroll
    for (int d = 0; d < cDOB; ++d) s[d] += fmaxf(xv * rus[c * cDOB + d], 0.f);
  }
  #pragma unroll
  for (int d = 0; d < cDOB; ++d) s[d] *= (1.0f / 9.0f);
  float u[cDOB];
  #pragma unroll
  for (int e = 0; e < cDOB; ++e) {
    float a = 0.f;
    #pragma unroll
    for (int d = 0; d < cDOB; ++d) a += s[d] * w1s[d * cDOB + e];
    u[e] = fmaxf(a, 0.f);
  }
  #pragma unroll
  for (int e = 0; e < cDOB; ++e) {
    float a = 0.f;
    #pragma unroll
    for (int d = 0; d < cDOB; ++d) a += u[d] * w2s[d * cDOB + e];
    vsh[tid][e] = fmaxf(a, 0.f);
  }
  __syncthreads();
  size_t zbase = (size_t)token0 * cD;
  for (int i = tid; i < 256 * cD; i += 256) {
    int tok = i / cD, col = i % cD;
    float val;
    if (col < cDM) {
      val = vsh[tok][col % cDOB];
    } else {
      int j = col - cDM;
      int tt = (token0 + tok) % cT;
      float st = (float)tt / tss[j & 7];
      val = (j < 8) ? sinf(st) : cosf(st);
    }
    Z[zbase + i] = val;
  }
}

// ---------------- fp32 tiled GEMM: C[M,N] = A[M,K] @ B[K,N] + bias (opt relu) ----------------
__global__ __launch_bounds__(256) void k_gemm(const float* __restrict__ A,
    const float* __restrict__ Bm, const float* __restrict__ bias,
    float* __restrict__ Cm, int Mr, int Nc, int Kd, int relu) {
  __shared__ float As[16][68];   // As[k][m]
  __shared__ float Bs[16][68];   // Bs[k][n]
  int tid = threadIdx.x;
  int tx = tid & 15, ty = tid >> 4;
  int n0 = blockIdx.x * 64, m0 = blockIdx.y * 64;
  float acc[4][4] = {{0.f}};
  for (int k0 = 0; k0 < Kd; k0 += 16) {
    {
      int row = tid >> 2, kq = (tid & 3) << 2;
      int gm = m0 + row, gk = k0 + kq;
      float4 av = make_float4(0.f, 0.f, 0.f, 0.f);
      if (gm < Mr) {
        const float* ap = A + (size_t)gm * Kd + gk;
        if (gk + 3 < Kd) av = *(const float4*)ap;
        else {
          if (gk + 0 < Kd) av.x = ap[0];
          if (gk + 1 < Kd) av.y = ap[1];
          if (gk + 2 < Kd) av.z = ap[2];
        }
      }
      As[kq + 0][row] = av.x; As[kq + 1][row] = av.y;
      As[kq + 2][row] = av.z; As[kq + 3][row] = av.w;
    }
    {
      int kr = tid >> 4, nc = (tid & 15) << 2;
      int gk = k0 + kr, gn = n0 + nc;
      float4 bv = make_float4(0.f, 0.f, 0.f, 0.f);
      if (gk < Kd && gn < Nc) {
        const float* bp = Bm + (size_t)gk * Nc + gn;
        if (gn + 3 < Nc) bv = *(const float4*)bp;
        else {
          bv.x = bp[0];
          if (gn + 1 < Nc) bv.y = bp[1];
          if (gn + 2 < Nc) bv.z = bp[2];
        }
      }
      *(float4*)&Bs[kr][nc] = bv;
    }
    __syncthreads();
    #pragma unroll
    for (int k = 0; k < 16; ++k) {
      float4 a = *(const float4*)&As[k][ty << 2];
      float4 b = *(const float4*)&Bs[k][tx << 2];
      acc[0][0] += a.x * b.x; acc[0][1] += a.x * b.y; acc[0][2] += a.x * b.z; acc[0][3] += a.x * b.w;
      acc[1][0] += a.y * b.x; acc[1][1] += a.y * b.y; acc[1][2] += a.y * b.z; acc[1][3] += a.y * b.w;
      acc[2][0] += a.z * b.x; acc[2][1] += a.z * b.y; acc[2][2] += a.z * b.z; acc[2][3] += a.z * b.w;
      acc[3][0] += a.w * b.x; acc[3][1] += a.w * b.y; acc[3][2] += a.w * b.z; acc[3][3] += a.w * b.w;
    }
    __syncthreads();
  }
  #pragma unroll
  for (int i = 0; i < 4; ++i) {
    int gm = m0 + (ty << 2) + i;
    if (gm >= Mr) continue;
    #pragma unroll
    for (int j = 0; j < 4; ++j) {
      int gn = n0 + (tx << 2) + j;
      if (gn >= Nc) continue;
      float v = acc[i][j] + (bias ? bias[gn] : 0.f);
      if (relu) v = fmaxf(v, 0.f);
      Cm[(size_t)gm * Nc + gn] = v;
    }
  }
}

// ---------------- flash attention fp32: grid (qb=8, h=4, b) ----------------
__global__ __launch_bounds__(256) void k_attn(const float* __restrict__ QKV,
    float* __restrict__ ATT) {
  __shared__ float Qs[cDH][68];       // Q transposed [d][r]
  __shared__ float KV[cDH * 68];      // union: K_t[d*68+c]  /  V[c*96+d]
  int tid = threadIdx.x;
  int tx = tid & 15, ty = tid >> 4;
  int qb = blockIdx.x, h = blockIdx.y, bl = blockIdx.z;
  size_t tokBase = (size_t)bl * cT;
  const float scale = 0.103142125f;   // 1/sqrt(94)
  for (int i = tid; i < 64 * cDH; i += 256) {
    int r = i / cDH, d = i % cDH;
    Qs[d][r] = QKV[(tokBase + qb * 64 + r) * 1128 + h * cDH + d];
  }
  float mrow[4], lrow[4], acc[4][6];
  #pragma unroll
  for (int i = 0; i < 4; ++i) {
    mrow[i] = -1e30f; lrow[i] = 0.f;
    #pragma unroll
    for (int k = 0; k < 6; ++k) acc[i][k] = 0.f;
  }
  for (int kt = 0; kt < 8; ++kt) {
    __syncthreads();
    for (int i = tid; i < 64 * cDH; i += 256) {   // stage K transposed
      int r = i / cDH, d = i % cDH;
      KV[d * 68 + r] = QKV[(tokBase + kt * 64 + r) * 1128 + cD + h * cDH + d];
    }
    __syncthreads();
    float sc[4][4] = {{0.f}};
    for (int d = 0; d < cDH; ++d) {
      float4 q4 = *(const float4*)&Qs[d][ty << 2];
      float4 k4 = *(const float4*)&KV[d * 68 + (tx << 2)];
      sc[0][0] += q4.x * k4.x; sc[0][1] += q4.x * k4.y; sc[0][2] += q4.x * k4.z; sc[0][3] += q4.x * k4.w;
      sc[1][0] += q4.y * k4.x; sc[1][1] += q4.y * k4.y; sc[1][2] += q4.y * k4.z; sc[1][3] += q4.y * k4.w;
      sc[2][0] += q4.z * k4.x; sc[2][1] += q4.z * k4.y; sc[2][2] += q4.z * k4.z; sc[2][3] += q4.z * k4.w;
      sc[3][0] += q4.w * k4.x; sc[3][1] += q4.w * k4.y; sc[3][2] += q4.w * k4.z; sc[3][3] += q4.w * k4.w;
    }
    float p[4][4];
    #pragma unroll
    for (int i = 0; i < 4; ++i) {
      #pragma unroll
      for (int j = 0; j < 4; ++j) sc[i][j] *= scale;
      float mx = fmaxf(fmaxf(sc[i][0], sc[i][1]), fmaxf(sc[i][2], sc[i][3]));
      for (int off = 8; off > 0; off >>= 1) mx = fmaxf(mx, __shfl_xor(mx, off, 16));
      float mnew = fmaxf(mrow[i], mx);
      float fsc = __expf(mrow[i] - mnew);
      float ps = 0.f;
      #pragma unroll
      for (int j = 0; j < 4; ++j) { p[i][j] = __expf(sc[i][j] - mnew); ps += p[i][j]; }
      for (int off = 8; off > 0; off >>= 1) ps += __shfl_xor(ps, off, 16);
      lrow[i] = lrow[i] * fsc + ps;
      mrow[i] = mnew;
      #pragma unroll
      for (int k = 0; k < 6; ++k) acc[i][k] *= fsc;
    }
    __syncthreads();
    for (int i = tid; i < 64 * cDH; i += 256) {   // stage V (overwrites K)
      int r = i / cDH, d = i % cDH;
      KV[r * 96 + d] = QKV[(tokBase + kt * 64 + r) * 1128 + 2 * cD + h * cDH + d];
    }
    __syncthreads();
    for (int c4 = 0; c4 < 64; c4 += 4) {
      #pragma unroll
      for (int cj = 0; cj < 4; ++cj) {
        int c = c4 + cj;
        float pv0 = __shfl(p[0][cj], c >> 2, 16);
        float pv1 = __shfl(p[1][cj], c >> 2, 16);
        float pv2 = __shfl(p[2][cj], c >> 2, 16);
        float pv3 = __shfl(p[3][cj], c >> 2, 16);
        const float* vrow = &KV[c * 96 + tx * 6];
        float2 va = *(const float2*)(vrow);
        float2 vb = *(const float2*)(vrow + 2);
        float2 vc = *(const float2*)(vrow + 4);
        acc[0][0] += pv0 * va.x; acc[0][1] += pv0 * va.y; acc[0][2] += pv0 * vb.x;
        acc[0][3] += pv0 * vb.y; acc[0][4] += pv0 * vc.x; acc[0][5] += pv0 * vc.y;
        acc[1][0] += pv1 * va.x; acc[1][1] += pv1 * va.y; acc[1][2] += pv1 * vb.x;
        acc[1][3] += pv1 * vb.y; acc[1][4] += pv1 * vc.x; acc[1][5] += pv1 * vc.y;
        acc[2][0] += pv2 * va.x; acc[2][1] += pv2 * va.y; acc[2][2] += pv2 * vb.x;
        acc[2][3] += pv2 * vb.y; acc[2][4] += pv2 * vc.x; acc[2][5] += pv2 * vc.y;
        acc[3][0] += pv3 * va.x; acc[3][1] += pv3 * va.y; acc[3][2] += pv3 * vb.x;
        acc[3][3] += pv3 * vb.y; acc[3][4] += pv3 * vc.x; acc[3][5] += pv3 * vc.y;
      }
    }
  }
  #pragma unroll
  for (int i = 0; i < 4; ++i) {
    float inv = 1.0f / lrow[i];
    size_t rowBase = (tokBase + qb * 64 + (ty << 2) + i) * (size_t)cD + h * cDH;
    #pragma unroll
    for (int k = 0; k < 6; ++k) {
      int d = tx * 6 + k;
      if (d < cDH) ATT[rowBase + d] = acc[i][k] * inv;
    }
  }
}

// ---------------- z = LN(z + y) over last dim D ----------------
__global__ __launch_bounds__(128) void k_addln(float* __restrict__ Z,
    const float* __restrict__ Y, const float* __restrict__ gam,
    const float* __restrict__ bet) {
  __shared__ float red[128];
  size_t base = (size_t)blockIdx.x * cD;
  int tid = threadIdx.x;
  float v[3];
  float sum = 0.f;
  #pragma unroll
  for (int i = 0; i < 3; ++i) {
    int c = tid + i * 128;
    float t = 0.f;
    if (c < cD) t = Z[base + c] + Y[base + c];
    v[i] = t; sum += t;
  }
  red[tid] = sum; __syncthreads();
  for (int s = 64; s > 0; s >>= 1) { if (tid < s) red[tid] += red[tid + s]; __syncthreads(); }
  float mean = red[0] / (float)cD;
  __syncthreads();
  float vs = 0.f;
  #pragma unroll
  for (int i = 0; i < 3; ++i) {
    int c = tid + i * 128;
    if (c < cD) { float d = v[i] - mean; vs += d * d; }
  }
  red[tid] = vs; __syncthreads();
  for (int s = 64; s > 0; s >>= 1) { if (tid < s) red[tid] += red[tid + s]; __syncthreads(); }
  float inv = rsqrtf(red[0] / (float)cD + cEPS);
  #pragma unroll
  for (int i = 0; i < 3; ++i) {
    int c = tid + i * 128;
    if (c < cD) Z[base + c] = (v[i] - mean) * inv * gam[c] + bet[c];
  }
}

// ---------------- et[b,d] = mean_t Z[b,t,d] ----------------
__global__ __launch_bounds__(384) void k_meant(const float* __restrict__ Z,
    float* __restrict__ et, int bStart) {
  int bl = blockIdx.x, d = threadIdx.x;
  if (d >= cD) return;
  float s = 0.f;
  for (int t = 0; t < cT; ++t) s += Z[((size_t)bl * cT + t) * cD + d];
  et[(size_t)(bStart + bl) * cD + d] = s * (1.0f / 512.0f);
}

// ---------------- final L2-normalize of concat feature ----------------
__global__ __launch_bounds__(128) void k_final(const float* __restrict__ fst,
    float* __restrict__ out) {
  __shared__ float red[128];
  int b = blockIdx.x, tid = threadIdx.x;
  float v[5]; float ss = 0.f;
  #pragma unroll
  for (int i = 0; i < 5; ++i) {
    v[i] = fst[(size_t)b * 640 + tid + i * 128];
    ss += v[i] * v[i];
  }
  red[tid] = ss; __syncthreads();
  for (int s = 64; s > 0; s >>= 1) { if (tid < s) red[tid] += red[tid + s]; __syncthreads(); }
  float inv = 1.0f / fmaxf(sqrtf(red[0]), 1e-12f);
  #pragma unroll
  for (int i = 0; i < 5; ++i) out[(size_t)b * 640 + tid + i * 128] = v[i] * inv;
}

extern "C" void kernel_launch(void* const* d_in, const int* in_sizes, int n_in,
                              void* d_out, int out_size, void* d_ws, size_t ws_size,
                              hipStream_t stream) {
  (void)in_sizes; (void)n_in; (void)out_size;
  const float* x     = (const float*)d_in[0];
  const float* w1r   = (const float*)d_in[1];
  const float* w1i   = (const float*)d_in[2];
  const float* convw = (const float*)d_in[3];
  const float* bnfg  = (const float*)d_in[4];
  const float* bnfb  = (const float*)d_in[5];
  const float* Ru    = (const float*)d_in[6];
  const float* Wg1   = (const float*)d_in[7];
  const float* Wg2   = (const float*)d_in[8];
  const float* Wqkv  = (const float*)d_in[9];
  const float* bqkv  = (const float*)d_in[10];
  const float* Wo    = (const float*)d_in[11];
  const float* bo    = (const float*)d_in[12];
  const float* ln1g  = (const float*)d_in[13];
  const float* ln1b  = (const float*)d_in[14];
  const float* W1    = (const float*)d_in[15];
  const float* b1    = (const float*)d_in[16];
  const float* W2    = (const float*)d_in[17];
  const float* b2    = (const float*)d_in[18];
  const float* ln2g  = (const float*)d_in[19];
  const float* ln2b  = (const float*)d_in[20];
  const float* Wp    = (const float*)d_in[21];
  const float* bp    = (const float*)d_in[22];
  const float* bnpg  = (const float*)d_in[23];
  const float* bnpb  = (const float*)d_in[24];

  // ---- fixed workspace layout (floats) ----
  float* W = (float*)d_ws;
  size_t wsFloats = ws_size / 4;
  float* fst = W;                       //  81920
  float* et  = fst + 81920;             //  48128
  float* etp = et + 48128;              //  65536
  float2* g  = (float2*)(etp + 65536);  //   1024 floats
  float* EF  = (float*)g + 1024;        // 147456
  float* efp = EF + 147456;             //  16384
  const size_t fixedFloats = 81920 + 48128 + 65536 + 1024 + 147456 + 16384; // 360448

  float* outF  = (float*)d_out;
  float* outft = outF + cB * 640;       // real-part-only [B,C,T] = 589824 floats

  if (wsFloats < fixedFloats) return;   // anti-fault guard

  // ---- choose transformer chunk scratch from ws ----
  int Bc = 0;
  float* chunk = nullptr;
  for (int c = 128; c >= 1; c >>= 1) {
    size_t need = (size_t)c * cT * (cD + 1128 + cD);
    if (fixedFloats + need <= wsFloats) { Bc = c; chunk = W + fixedFloats; break; }
  }
  bool haveChunk = (Bc > 0);

  // ---- transformer branch (chunked over batch) ----
  if (haveChunk) {
    float* Zb   = chunk;
    float* QKVb = Zb + (size_t)Bc * cT * cD;
    float* ATTb = QKVb + (size_t)Bc * cT * 1128;
    for (int b0 = 0; b0 < cB; b0 += Bc) {
      int ntok = Bc * cT;
      k_raindrop<<<ntok / 256, 256, 0, stream>>>(x, Ru, Wg1, Wg2, Zb, b0);
      for (int l = 0; l < 3; ++l) {
        k_gemm<<<dim3((1128 + 63) / 64, ntok / 64), 256, 0, stream>>>(
            Zb, Wqkv + (size_t)l * cD * 1128, bqkv + (size_t)l * 1128, QKVb, ntok, 1128, cD, 0);
        k_attn<<<dim3(8, 4, Bc), 256, 0, stream>>>(QKVb, ATTb);
        k_gemm<<<dim3((cD + 63) / 64, ntok / 64), 256, 0, stream>>>(
            ATTb, Wo + (size_t)l * cD * cD, bo + (size_t)l * cD, QKVb, ntok, cD, cD, 0);
        k_addln<<<ntok, 128, 0, stream>>>(Zb, QKVb, ln1g + l * cD, ln1b + l * cD);
        k_gemm<<<dim3((cNHID + 63) / 64, ntok / 64), 256, 0, stream>>>(
            Zb, W1 + (size_t)l * cD * cNHID, b1 + (size_t)l * cNHID, QKVb, ntok, cNHID, cD, 1);
        k_gemm<<<dim3((cD + 63) / 64, ntok / 64), 256, 0, stream>>>(
            QKVb, W2 + (size_t)l * cNHID * cD, b2 + (size_t)l * cD, ATTb, ntok, cD, cNHID, 0);
        k_addln<<<ntok, 128, 0, stream>>>(Zb, ATTb, ln2g + l * cD, ln2b + l * cD);
      }
      k_meant<<<Bc, 384, 0, stream>>>(Zb, et, b0);
    }
    // projection et @ Wp + bp, relu -> etp
    k_gemm<<<dim3(cT / 64, cB / 64), 256, 0, stream>>>(et, Wp, bp, etp, cB, cT, cD, 1);
  }

  // ---- spectral branch ----
  k_chirp<<<1, 512, 0, stream>>>(g);
  k_spectral<<<cB, 512, 0, stream>>>(x, w1r, w1i, g, outft, EF);
  k_convef<<<(cB * 2 * cM + 255) / 256, 256, 0, stream>>>(EF, convw, efp);
  k_bn<<<2 * cM, 128, 0, stream>>>(efp, bnfg, bnfb, fst, 2 * cM, 640, 0, 1);

  if (haveChunk)
    k_bn<<<cT, 128, 0, stream>>>(etp, bnpg, bnpb, fst, cT, 640, 2 * cM, 0);

  k_final<<<cB, 128, 0, stream>>>(fst, outF);
}

// Round 5
// 6332.206 us; speedup vs baseline: 1.5792x; 1.5792x over previous
//
#include <hip/hip_runtime.h>
#include <math.h>

constexpr int cB = 128;
constexpr int cC = 9;
constexpr int cT = 512;
constexpr int cM = 64;
constexpr int cDOB = 40;
constexpr int cDM = 360;
constexpr int cD = 376;       // d_model + d_pe
constexpr int cDH = 94;
constexpr int cNHID = 720;
constexpr float cEPS = 1e-5f;
constexpr float cPI = 3.14159265358979323846f;

typedef __attribute__((ext_vector_type(8))) short short8b;  // 8 bf16
typedef __attribute__((ext_vector_type(4))) float f32x4;

__device__ __forceinline__ short f2b(float f) {
  union { float f; unsigned u; } c; c.f = f;
  unsigned r = (c.u + 0x7fffu + ((c.u >> 16) & 1u)) >> 16;  // RNE
  return (short)r;
}

// ---------------- chirp kernel g = ifft(chirp) ----------------
__global__ void k_chirp(float2* __restrict__ g) {
  int d = threadIdx.x;  // 512 threads
  float re = 0.f, im = 0.f;
  for (int k = 0; k < cT; ++k) {
    int q = (k * k) & 2047;
    int p = (k * d) & 511;
    float th = cPI * ((float)p * (1.0f / 256.0f) - (float)q * (1.0f / 1024.0f));
    float s, c;
    sincosf(th, &s, &c);
    re += c; im += s;
  }
  g[d] = make_float2(re * (1.0f / 512.0f), im * (1.0f / 512.0f));
}

// ---------------- spectral branch: frft modes, out_ft (real part), EF ----------------
__global__ __launch_bounds__(512) void k_spectral(
    const float* __restrict__ x, const float* __restrict__ w1r,
    const float* __restrict__ w1i, const float2* __restrict__ g,
    float* __restrict__ outft, float* __restrict__ EF) {
  __shared__ float xc[cC][cT];
  __shared__ float2 gs[cT];
  __shared__ float2 xfr[cC][cM];
  int b = blockIdx.x, tid = threadIdx.x;
  for (int i = tid; i < cC * cT; i += 512)
    xc[i / cT][i % cT] = cosf(x[(size_t)b * cC * cT + i]);
  for (int i = tid; i < cT; i += 512) gs[i] = g[i];
  __syncthreads();
  for (int idx = tid; idx < cC * cM; idx += 512) {
    int c = idx / cM, m = idx % cM;
    float re = 0.f, im = 0.f;
    for (int t = 0; t < cT; ++t) {
      float xv = xc[c][t];
      float2 gv = gs[(m - t) & (cT - 1)];
      re += xv * gv.x; im += xv * gv.y;
    }
    xfr[c][m] = make_float2(re, im);
  }
  __syncthreads();
  for (int idx = tid; idx < cC * cM; idx += 512) {
    int o = idx / cM, m = idx % cM;
    float re = 0.f, im = 0.f;
    #pragma unroll
    for (int i = 0; i < cC; ++i) {
      float2 xv = xfr[i][m];
      float wr = w1r[(i * cC + o) * cM + m];
      float wi = w1i[(i * cC + o) * cM + m];
      re += xv.x * wr - xv.y * wi;
      im += xv.x * wi + xv.y * wr;
    }
    outft[(size_t)(b * cC + o) * cT + m] = re;   // real part only
    EF[(b * cC + o) * (2 * cM) + m] = sqrtf(re * re + im * im);
    EF[(b * cC + o) * (2 * cM) + cM + m] = atan2f(im, re);
  }
  for (int idx = tid; idx < cC * (cT - cM); idx += 512) {
    int o = idx / (cT - cM);
    int r = idx % (cT - cM);
    outft[(size_t)(b * cC + o) * cT + cM + r] = 0.f;
  }
}

// ---------------- conv1d C->1 over feature axis ----------------
__global__ void k_convef(const float* __restrict__ EF, const float* __restrict__ cw,
                         float* __restrict__ efp) {
  int i = blockIdx.x * blockDim.x + threadIdx.x;
  if (i >= cB * 2 * cM) return;
  int b = i / (2 * cM), f = i % (2 * cM);
  float acc = 0.f;
  #pragma unroll
  for (int c = 0; c < cC; ++c) {
    const float* row = EF + (b * cC + c) * (2 * cM);
    if (f > 0) acc += row[f - 1] * cw[c * 3 + 0];
    acc += row[f] * cw[c * 3 + 1];
    if (f < 2 * cM - 1) acc += row[f + 1] * cw[c * 3 + 2];
  }
  efp[i] = acc;
}

// ---------------- batchnorm over batch dim ----------------
__global__ __launch_bounds__(128) void k_bn(const float* __restrict__ in,
    const float* __restrict__ gam, const float* __restrict__ bet,
    float* __restrict__ dst, int F, int stride, int off, int reluAfter) {
  __shared__ float red[128];
  int f = blockIdx.x, bt = threadIdx.x;
  float v = in[(size_t)bt * F + f];
  red[bt] = v; __syncthreads();
  for (int s = 64; s > 0; s >>= 1) { if (bt < s) red[bt] += red[bt + s]; __syncthreads(); }
  float mean = red[0] * (1.0f / 128.0f);
  __syncthreads();
  float d = v - mean;
  red[bt] = d * d; __syncthreads();
  for (int s = 64; s > 0; s >>= 1) { if (bt < s) red[bt] += red[bt + s]; __syncthreads(); }
  float var = red[0] * (1.0f / 128.0f);
  float o = d * rsqrtf(var + cEPS) * gam[f] + bet[f];
  if (reluAfter) o = fmaxf(o, 0.f);
  dst[(size_t)bt * stride + off + f] = o;
}

// ---------------- raindrop branch -> z0 [Bc,T,D] ----------------
__global__ __launch_bounds__(256) void k_raindrop(const float* __restrict__ x,
    const float* __restrict__ Ru, const float* __restrict__ Wg1,
    const float* __restrict__ Wg2, float* __restrict__ Z, int bStart) {
  __shared__ float w1s[cDOB * cDOB], w2s[cDOB * cDOB], rus[cDM], tss[8];
  __shared__ float vsh[256][cDOB];
  int tid = threadIdx.x;
  for (int i = tid; i < cDOB * cDOB; i += 256) { w1s[i] = Wg1[i]; w2s[i] = Wg2[i]; }
  for (int i = tid; i < cDM; i += 256) rus[i] = Ru[i];
  if (tid < 8) tss[tid] = powf(100.0f, (float)tid * (1.0f / 7.0f));
  __syncthreads();
  int token0 = blockIdx.x * 256;
  int token = token0 + tid;
  int bl = token / cT, t = token % cT;
  int bg = bStart + bl;
  float s[cDOB];
  #pragma unroll
  for (int d = 0; d < cDOB; ++d) s[d] = 0.f;
  #pragma unroll
  for (int c = 0; c < cC; ++c) {
    float xv = x[((size_t)bg * cC + c) * cT + t];
    #pragma unroll
    for (int d = 0; d < cDOB; ++d) s[d] += fmaxf(xv * rus[c * cDOB + d], 0.f);
  }
  #pragma unroll
  for (int d = 0; d < cDOB; ++d) s[d] *= (1.0f / 9.0f);
  float u[cDOB];
  #pragma unroll
  for (int e = 0; e < cDOB; ++e) {
    float a = 0.f;
    #pragma unroll
    for (int d = 0; d < cDOB; ++d) a += s[d] * w1s[d * cDOB + e];
    u[e] = fmaxf(a, 0.f);
  }
  #pragma unroll
  for (int e = 0; e < cDOB; ++e) {
    float a = 0.f;
    #pragma unroll
    for (int d = 0; d < cDOB; ++d) a += u[d] * w2s[d * cDOB + e];
    vsh[tid][e] = fmaxf(a, 0.f);
  }
  __syncthreads();
  size_t zbase = (size_t)token0 * cD;
  for (int i = tid; i < 256 * cD; i += 256) {
    int tok = i / cD, col = i % cD;
    float val;
    if (col < cDM) {
      val = vsh[tok][col % cDOB];
    } else {
      int j = col - cDM;
      int tt = (token0 + tok) % cT;
      float st = (float)tt / tss[j & 7];
      val = (j < 8) ? sinf(st) : cosf(st);
    }
    Z[zbase + i] = val;
  }
}

// ---------------- transpose+convert: in[K][N] fp32 -> out[N][K] bf16 ----------------
__global__ __launch_bounds__(256) void k_cvtT(const float* __restrict__ in,
    short* __restrict__ out, int K, int N) {
  __shared__ float tile[32][33];
  int kb = blockIdx.x * 32, nb = blockIdx.y * 32;
  int tx = threadIdx.x & 31, ty = threadIdx.x >> 5;  // 32x8
  for (int i = ty; i < 32; i += 8) {
    int k = kb + i, n = nb + tx;
    tile[i][tx] = (k < K && n < N) ? in[(size_t)k * N + n] : 0.f;
  }
  __syncthreads();
  for (int i = ty; i < 32; i += 8) {
    int n = nb + i, k = kb + tx;
    if (n < N && k < K) out[(size_t)n * K + k] = f2b(tile[tx][i]);
  }
}

// ---------------- bf16 MFMA GEMM: C[M,N] = A[M,K](f32) @ Bt[N,K](bf16)^T + bias ----------------
// tile 64x64, 4 waves, each wave 32x32 (2x2 frags of 16x16x32)
__global__ __launch_bounds__(256) void k_gemm_mfma(
    const float* __restrict__ A, const short* __restrict__ Bt,
    const float* __restrict__ bias, float* __restrict__ Cm,
    int Mr, int Nc, int Kd, int relu) {
  __shared__ short As[64][40];   // +8 pad: 80B row stride (5x16B)
  __shared__ short Bs[64][40];
  int tid = threadIdx.x;
  int m0 = blockIdx.y * 64, n0 = blockIdx.x * 64;
  int w = tid >> 6, l = tid & 63;
  int wm = w >> 1, wn = w & 1;
  int lr = l & 15, lq = l >> 4;
  f32x4 acc[2][2];
  #pragma unroll
  for (int i = 0; i < 2; ++i)
    #pragma unroll
    for (int j = 0; j < 2; ++j)
      #pragma unroll
      for (int r = 0; r < 4; ++r) acc[i][j][r] = 0.f;
  int nK = (Kd + 31) >> 5;
  for (int ks = 0; ks < nK; ++ks) {
    int k0 = ks << 5;
    {   // stage A (fp32 -> bf16)
      int m = tid >> 2, kq = (tid & 3) << 3;
      int gm = m0 + m, gk = k0 + kq;
      float v[8];
      if (gm < Mr && gk + 7 < Kd) {
        float4 p0 = *(const float4*)(A + (size_t)gm * Kd + gk);
        float4 p1 = *(const float4*)(A + (size_t)gm * Kd + gk + 4);
        v[0]=p0.x; v[1]=p0.y; v[2]=p0.z; v[3]=p0.w;
        v[4]=p1.x; v[5]=p1.y; v[6]=p1.z; v[7]=p1.w;
      } else {
        #pragma unroll
        for (int j = 0; j < 8; ++j)
          v[j] = (gm < Mr && gk + j < Kd) ? A[(size_t)gm * Kd + gk + j] : 0.f;
      }
      short tmp[8];
      #pragma unroll
      for (int j = 0; j < 8; ++j) tmp[j] = f2b(v[j]);
      *(short8b*)&As[m][kq] = *(short8b*)tmp;
    }
    {   // stage B (bf16 passthrough)
      int n = tid >> 2, kq = (tid & 3) << 3;
      int gn = n0 + n, gk = k0 + kq;
      short tmp[8];
      if (gn < Nc && gk + 7 < Kd) {
        *(short8b*)tmp = *(const short8b*)(Bt + (size_t)gn * Kd + gk);
      } else {
        #pragma unroll
        for (int j = 0; j < 8; ++j)
          tmp[j] = (gn < Nc && gk + j < Kd) ? Bt[(size_t)gn * Kd + gk + j] : (short)0;
      }
      *(short8b*)&Bs[n][kq] = *(short8b*)tmp;
    }
    __syncthreads();
    short8b af[2], bfr[2];
    #pragma unroll
    for (int f = 0; f < 2; ++f) {
      af[f]  = *(short8b*)&As[wm * 32 + f * 16 + lr][lq * 8];
      bfr[f] = *(short8b*)&Bs[wn * 32 + f * 16 + lr][lq * 8];
    }
    #pragma unroll
    for (int i = 0; i < 2; ++i)
      #pragma unroll
      for (int j = 0; j < 2; ++j)
        acc[i][j] = __builtin_amdgcn_mfma_f32_16x16x32_bf16(af[i], bfr[j], acc[i][j], 0, 0, 0);
    __syncthreads();
  }
  // epilogue: C/D layout col=lane&15, row=(lane>>4)*4+reg  [m89-verified]
  #pragma unroll
  for (int i = 0; i < 2; ++i)
    #pragma unroll
    for (int j = 0; j < 2; ++j) {
      int gn = n0 + wn * 32 + j * 16 + lr;
      if (gn >= Nc) continue;
      float bv = bias ? bias[gn] : 0.f;
      int gmb = m0 + wm * 32 + i * 16 + lq * 4;
      #pragma unroll
      for (int r = 0; r < 4; ++r) {
        int gm = gmb + r;
        if (gm >= Mr) continue;
        float vv = acc[i][j][r] + bv;
        if (relu) vv = fmaxf(vv, 0.f);
        Cm[(size_t)gm * Nc + gn] = vv;
      }
    }
}

// ---------------- fp32 tiled GEMM (small cases: final projection) ----------------
__global__ __launch_bounds__(256) void k_gemm(const float* __restrict__ A,
    const float* __restrict__ Bm, const float* __restrict__ bias,
    float* __restrict__ Cm, int Mr, int Nc, int Kd, int relu) {
  __shared__ float As[16][68];
  __shared__ float Bs[16][68];
  int tid = threadIdx.x;
  int tx = tid & 15, ty = tid >> 4;
  int n0 = blockIdx.x * 64, m0 = blockIdx.y * 64;
  float acc[4][4] = {{0.f}};
  for (int k0 = 0; k0 < Kd; k0 += 16) {
    {
      int row = tid >> 2, kq = (tid & 3) << 2;
      int gm = m0 + row, gk = k0 + kq;
      float4 av = make_float4(0.f, 0.f, 0.f, 0.f);
      if (gm < Mr) {
        const float* ap = A + (size_t)gm * Kd + gk;
        if (gk + 3 < Kd) av = *(const float4*)ap;
        else {
          if (gk + 0 < Kd) av.x = ap[0];
          if (gk + 1 < Kd) av.y = ap[1];
          if (gk + 2 < Kd) av.z = ap[2];
        }
      }
      As[kq + 0][row] = av.x; As[kq + 1][row] = av.y;
      As[kq + 2][row] = av.z; As[kq + 3][row] = av.w;
    }
    {
      int kr = tid >> 4, nc = (tid & 15) << 2;
      int gk = k0 + kr, gn = n0 + nc;
      float4 bv = make_float4(0.f, 0.f, 0.f, 0.f);
      if (gk < Kd && gn < Nc) {
        const float* bp = Bm + (size_t)gk * Nc + gn;
        if (gn + 3 < Nc) bv = *(const float4*)bp;
        else {
          bv.x = bp[0];
          if (gn + 1 < Nc) bv.y = bp[1];
          if (gn + 2 < Nc) bv.z = bp[2];
        }
      }
      *(float4*)&Bs[kr][nc] = bv;
    }
    __syncthreads();
    #pragma unroll
    for (int k = 0; k < 16; ++k) {
      float4 a = *(const float4*)&As[k][ty << 2];
      float4 b = *(const float4*)&Bs[k][tx << 2];
      acc[0][0] += a.x * b.x; acc[0][1] += a.x * b.y; acc[0][2] += a.x * b.z; acc[0][3] += a.x * b.w;
      acc[1][0] += a.y * b.x; acc[1][1] += a.y * b.y; acc[1][2] += a.y * b.z; acc[1][3] += a.y * b.w;
      acc[2][0] += a.z * b.x; acc[2][1] += a.z * b.y; acc[2][2] += a.z * b.z; acc[2][3] += a.z * b.w;
      acc[3][0] += a.w * b.x; acc[3][1] += a.w * b.y; acc[3][2] += a.w * b.z; acc[3][3] += a.w * b.w;
    }
    __syncthreads();
  }
  #pragma unroll
  for (int i = 0; i < 4; ++i) {
    int gm = m0 + (ty << 2) + i;
    if (gm >= Mr) continue;
    #pragma unroll
    for (int j = 0; j < 4; ++j) {
      int gn = n0 + (tx << 2) + j;
      if (gn >= Nc) continue;
      float v = acc[i][j] + (bias ? bias[gn] : 0.f);
      if (relu) v = fmaxf(v, 0.f);
      Cm[(size_t)gm * Nc + gn] = v;
    }
  }
}

// ---------------- flash attention fp32: grid (qb=8, h=4, b) ----------------
__global__ __launch_bounds__(256) void k_attn(const float* __restrict__ QKV,
    float* __restrict__ ATT) {
  __shared__ float Qs[cDH][68];
  __shared__ float KV[cDH * 68];
  int tid = threadIdx.x;
  int tx = tid & 15, ty = tid >> 4;
  int qb = blockIdx.x, h = blockIdx.y, bl = blockIdx.z;
  size_t tokBase = (size_t)bl * cT;
  const float scale = 0.103142125f;   // 1/sqrt(94)
  for (int i = tid; i < 64 * cDH; i += 256) {
    int r = i / cDH, d = i % cDH;
    Qs[d][r] = QKV[(tokBase + qb * 64 + r) * 1128 + h * cDH + d];
  }
  float mrow[4], lrow[4], acc[4][6];
  #pragma unroll
  for (int i = 0; i < 4; ++i) {
    mrow[i] = -1e30f; lrow[i] = 0.f;
    #pragma unroll
    for (int k = 0; k < 6; ++k) acc[i][k] = 0.f;
  }
  for (int kt = 0; kt < 8; ++kt) {
    __syncthreads();
    for (int i = tid; i < 64 * cDH; i += 256) {
      int r = i / cDH, d = i % cDH;
      KV[d * 68 + r] = QKV[(tokBase + kt * 64 + r) * 1128 + cD + h * cDH + d];
    }
    __syncthreads();
    float sc[4][4] = {{0.f}};
    for (int d = 0; d < cDH; ++d) {
      float4 q4 = *(const float4*)&Qs[d][ty << 2];
      float4 k4 = *(const float4*)&KV[d * 68 + (tx << 2)];
      sc[0][0] += q4.x * k4.x; sc[0][1] += q4.x * k4.y; sc[0][2] += q4.x * k4.z; sc[0][3] += q4.x * k4.w;
      sc[1][0] += q4.y * k4.x; sc[1][1] += q4.y * k4.y; sc[1][2] += q4.y * k4.z; sc[1][3] += q4.y * k4.w;
      sc[2][0] += q4.z * k4.x; sc[2][1] += q4.z * k4.y; sc[2][2] += q4.z * k4.z; sc[2][3] += q4.z * k4.w;
      sc[3][0] += q4.w * k4.x; sc[3][1] += q4.w * k4.y; sc[3][2] += q4.w * k4.z; sc[3][3] += q4.w * k4.w;
    }
    float p[4][4];
    #pragma unroll
    for (int i = 0; i < 4; ++i) {
      #pragma unroll
      for (int j = 0; j < 4; ++j) sc[i][j] *= scale;
      float mx = fmaxf(fmaxf(sc[i][0], sc[i][1]), fmaxf(sc[i][2], sc[i][3]));
      for (int off = 8; off > 0; off >>= 1) mx = fmaxf(mx, __shfl_xor(mx, off, 16));
      float mnew = fmaxf(mrow[i], mx);
      float fsc = __expf(mrow[i] - mnew);
      float ps = 0.f;
      #pragma unroll
      for (int j = 0; j < 4; ++j) { p[i][j] = __expf(sc[i][j] - mnew); ps += p[i][j]; }
      for (int off = 8; off > 0; off >>= 1) ps += __shfl_xor(ps, off, 16);
      lrow[i] = lrow[i] * fsc + ps;
      mrow[i] = mnew;
      #pragma unroll
      for (int k = 0; k < 6; ++k) acc[i][k] *= fsc;
    }
    __syncthreads();
    for (int i = tid; i < 64 * cDH; i += 256) {
      int r = i / cDH, d = i % cDH;
      KV[r * 96 + d] = QKV[(tokBase + kt * 64 + r) * 1128 + 2 * cD + h * cDH + d];
    }
    __syncthreads();
    for (int c4 = 0; c4 < 64; c4 += 4) {
      #pragma unroll
      for (int cj = 0; cj < 4; ++cj) {
        int c = c4 + cj;
        float pv0 = __shfl(p[0][cj], c >> 2, 16);
        float pv1 = __shfl(p[1][cj], c >> 2, 16);
        float pv2 = __shfl(p[2][cj], c >> 2, 16);
        float pv3 = __shfl(p[3][cj], c >> 2, 16);
        const float* vrow = &KV[c * 96 + tx * 6];
        float2 va = *(const float2*)(vrow);
        float2 vb = *(const float2*)(vrow + 2);
        float2 vc = *(const float2*)(vrow + 4);
        acc[0][0] += pv0 * va.x; acc[0][1] += pv0 * va.y; acc[0][2] += pv0 * vb.x;
        acc[0][3] += pv0 * vb.y; acc[0][4] += pv0 * vc.x; acc[0][5] += pv0 * vc.y;
        acc[1][0] += pv1 * va.x; acc[1][1] += pv1 * va.y; acc[1][2] += pv1 * vb.x;
        acc[1][3] += pv1 * vb.y; acc[1][4] += pv1 * vc.x; acc[1][5] += pv1 * vc.y;
        acc[2][0] += pv2 * va.x; acc[2][1] += pv2 * va.y; acc[2][2] += pv2 * vb.x;
        acc[2][3] += pv2 * vb.y; acc[2][4] += pv2 * vc.x; acc[2][5] += pv2 * vc.y;
        acc[3][0] += pv3 * va.x; acc[3][1] += pv3 * va.y; acc[3][2] += pv3 * vb.x;
        acc[3][3] += pv3 * vb.y; acc[3][4] += pv3 * vc.x; acc[3][5] += pv3 * vc.y;
      }
    }
  }
  #pragma unroll
  for (int i = 0; i < 4; ++i) {
    float inv = 1.0f / lrow[i];
    size_t rowBase = (tokBase + qb * 64 + (ty << 2) + i) * (size_t)cD + h * cDH;
    #pragma unroll
    for (int k = 0; k < 6; ++k) {
      int d = tx * 6 + k;
      if (d < cDH) ATT[rowBase + d] = acc[i][k] * inv;
    }
  }
}

// ---------------- z = LN(z + y) over last dim D ----------------
__global__ __launch_bounds__(128) void k_addln(float* __restrict__ Z,
    const float* __restrict__ Y, const float* __restrict__ gam,
    const float* __restrict__ bet) {
  __shared__ float red[128];
  size_t base = (size_t)blockIdx.x * cD;
  int tid = threadIdx.x;
  float v[3];
  float sum = 0.f;
  #pragma unroll
  for (int i = 0; i < 3; ++i) {
    int c = tid + i * 128;
    float t = 0.f;
    if (c < cD) t = Z[base + c] + Y[base + c];
    v[i] = t; sum += t;
  }
  red[tid] = sum; __syncthreads();
  for (int s = 64; s > 0; s >>= 1) { if (tid < s) red[tid] += red[tid + s]; __syncthreads(); }
  float mean = red[0] / (float)cD;
  __syncthreads();
  float vs = 0.f;
  #pragma unroll
  for (int i = 0; i < 3; ++i) {
    int c = tid + i * 128;
    if (c < cD) { float d = v[i] - mean; vs += d * d; }
  }
  red[tid] = vs; __syncthreads();
  for (int s = 64; s > 0; s >>= 1) { if (tid < s) red[tid] += red[tid + s]; __syncthreads(); }
  float inv = rsqrtf(red[0] / (float)cD + cEPS);
  #pragma unroll
  for (int i = 0; i < 3; ++i) {
    int c = tid + i * 128;
    if (c < cD) Z[base + c] = (v[i] - mean) * inv * gam[c] + bet[c];
  }
}

// ---------------- et[b,d] = mean_t Z[b,t,d] ----------------
__global__ __launch_bounds__(384) void k_meant(const float* __restrict__ Z,
    float* __restrict__ et, int bStart) {
  int bl = blockIdx.x, d = threadIdx.x;
  if (d >= cD) return;
  float s = 0.f;
  for (int t = 0; t < cT; ++t) s += Z[((size_t)bl * cT + t) * cD + d];
  et[(size_t)(bStart + bl) * cD + d] = s * (1.0f / 512.0f);
}

// ---------------- final L2-normalize ----------------
__global__ __launch_bounds__(128) void k_final(const float* __restrict__ fst,
    float* __restrict__ out) {
  __shared__ float red[128];
  int b = blockIdx.x, tid = threadIdx.x;
  float v[5]; float ss = 0.f;
  #pragma unroll
  for (int i = 0; i < 5; ++i) {
    v[i] = fst[(size_t)b * 640 + tid + i * 128];
    ss += v[i] * v[i];
  }
  red[tid] = ss; __syncthreads();
  for (int s = 64; s > 0; s >>= 1) { if (tid < s) red[tid] += red[tid + s]; __syncthreads(); }
  float inv = 1.0f / fmaxf(sqrtf(red[0]), 1e-12f);
  #pragma unroll
  for (int i = 0; i < 5; ++i) out[(size_t)b * 640 + tid + i * 128] = v[i] * inv;
}

extern "C" void kernel_launch(void* const* d_in, const int* in_sizes, int n_in,
                              void* d_out, int out_size, void* d_ws, size_t ws_size,
                              hipStream_t stream) {
  (void)in_sizes; (void)n_in; (void)out_size;
  const float* x     = (const float*)d_in[0];
  const float* w1r   = (const float*)d_in[1];
  const float* w1i   = (const float*)d_in[2];
  const float* convw = (const float*)d_in[3];
  const float* bnfg  = (const float*)d_in[4];
  const float* bnfb  = (const float*)d_in[5];
  const float* Ru    = (const float*)d_in[6];
  const float* Wg1   = (const float*)d_in[7];
  const float* Wg2   = (const float*)d_in[8];
  const float* Wqkv  = (const float*)d_in[9];
  const float* bqkv  = (const float*)d_in[10];
  const float* Wo    = (const float*)d_in[11];
  const float* bo    = (const float*)d_in[12];
  const float* ln1g  = (const float*)d_in[13];
  const float* ln1b  = (const float*)d_in[14];
  const float* W1    = (const float*)d_in[15];
  const float* b1    = (const float*)d_in[16];
  const float* W2    = (const float*)d_in[17];
  const float* b2    = (const float*)d_in[18];
  const float* ln2g  = (const float*)d_in[19];
  const float* ln2b  = (const float*)d_in[20];
  const float* Wp    = (const float*)d_in[21];
  const float* bp    = (const float*)d_in[22];
  const float* bnpg  = (const float*)d_in[23];
  const float* bnpb  = (const float*)d_in[24];

  // ---- fixed workspace layout (floats) ----
  float* W = (float*)d_ws;
  size_t wsFloats = ws_size / 4;
  float* fst = W;                       //  81920
  float* et  = fst + 81920;             //  48128
  float* etp = et + 48128;              //  65536
  float2* g  = (float2*)(etp + 65536);  //   1024 floats
  float* EF  = (float*)g + 1024;        // 147456
  float* efp = EF + 147456;             //  16384
  short* bfw = (short*)(efp + 16384);   // bf16 weights: 3,320,832 elems -> 1,660,416 fl
  const size_t bfwFloats = 1660416;
  const size_t fixedFloats = 81920 + 48128 + 65536 + 1024 + 147456 + 16384 + bfwFloats;

  // bf16 transposed weight offsets (in elems)
  const size_t oQKV = 0;                      // [3][1128][376]
  const size_t oWO  = oQKV + (size_t)3 * 1128 * 376;   // [3][376][376]
  const size_t oW1  = oWO  + (size_t)3 * 376 * 376;    // [3][720][376]
  const size_t oW2  = oW1  + (size_t)3 * 720 * 376;    // [3][376][720]

  float* outF  = (float*)d_out;
  float* outft = outF + cB * 640;       // real-part-only [B,C,T]

  if (wsFloats < fixedFloats) return;   // anti-fault guard

  // ---- choose transformer chunk scratch from ws ----
  int Bc = 0;
  float* chunk = nullptr;
  for (int c = 128; c >= 1; c >>= 1) {
    size_t need = (size_t)c * cT * (cD + 1128 + cD);
    if (fixedFloats + need <= wsFloats) { Bc = c; chunk = W + fixedFloats; break; }
  }
  bool haveChunk = (Bc > 0);

  if (haveChunk) {
    // ---- one-time weight convert+transpose to bf16 [N][K] ----
    for (int l = 0; l < 3; ++l) {
      k_cvtT<<<dim3(12, 36), 256, 0, stream>>>(Wqkv + (size_t)l * cD * 1128,
          bfw + oQKV + (size_t)l * 1128 * 376, cD, 1128);
      k_cvtT<<<dim3(12, 12), 256, 0, stream>>>(Wo + (size_t)l * cD * cD,
          bfw + oWO + (size_t)l * 376 * 376, cD, cD);
      k_cvtT<<<dim3(12, 23), 256, 0, stream>>>(W1 + (size_t)l * cD * cNHID,
          bfw + oW1 + (size_t)l * 720 * 376, cD, cNHID);
      k_cvtT<<<dim3(23, 12), 256, 0, stream>>>(W2 + (size_t)l * cNHID * cD,
          bfw + oW2 + (size_t)l * 376 * 720, cNHID, cD);
    }

    float* Zb   = chunk;
    float* QKVb = Zb + (size_t)Bc * cT * cD;
    float* ATTb = QKVb + (size_t)Bc * cT * 1128;
    for (int b0 = 0; b0 < cB; b0 += Bc) {
      int ntok = Bc * cT;
      k_raindrop<<<ntok / 256, 256, 0, stream>>>(x, Ru, Wg1, Wg2, Zb, b0);
      for (int l = 0; l < 3; ++l) {
        k_gemm_mfma<<<dim3(18, ntok / 64), 256, 0, stream>>>(
            Zb, bfw + oQKV + (size_t)l * 1128 * 376,
            bqkv + (size_t)l * 1128, QKVb, ntok, 1128, cD, 0);
        k_attn<<<dim3(8, 4, Bc), 256, 0, stream>>>(QKVb, ATTb);
        k_gemm_mfma<<<dim3(6, ntok / 64), 256, 0, stream>>>(
            ATTb, bfw + oWO + (size_t)l * 376 * 376,
            bo + (size_t)l * cD, QKVb, ntok, cD, cD, 0);
        k_addln<<<ntok, 128, 0, stream>>>(Zb, QKVb, ln1g + l * cD, ln1b + l * cD);
        k_gemm_mfma<<<dim3(12, ntok / 64), 256, 0, stream>>>(
            Zb, bfw + oW1 + (size_t)l * 720 * 376,
            b1 + (size_t)l * cNHID, QKVb, ntok, cNHID, cD, 1);
        k_gemm_mfma<<<dim3(6, ntok / 64), 256, 0, stream>>>(
            QKVb, bfw + oW2 + (size_t)l * 376 * 720,
            b2 + (size_t)l * cD, ATTb, ntok, cD, cNHID, 0);
        k_addln<<<ntok, 128, 0, stream>>>(Zb, ATTb, ln2g + l * cD, ln2b + l * cD);
      }
      k_meant<<<Bc, 384, 0, stream>>>(Zb, et, b0);
    }
    // projection et @ Wp + bp, relu -> etp (small, stays fp32)
    k_gemm<<<dim3(cT / 64, cB / 64), 256, 0, stream>>>(et, Wp, bp, etp, cB, cT, cD, 1);
  }

  // ---- spectral branch ----
  k_chirp<<<1, 512, 0, stream>>>(g);
  k_spectral<<<cB, 512, 0, stream>>>(x, w1r, w1i, g, outft, EF);
  k_convef<<<(cB * 2 * cM + 255) / 256, 256, 0, stream>>>(EF, convw, efp);
  k_bn<<<2 * cM, 128, 0, stream>>>(efp, bnfg, bnfb, fst, 2 * cM, 640, 0, 1);

  if (haveChunk)
    k_bn<<<cT, 128, 0, stream>>>(etp, bnpg, bnpb, fst, cT, 640, 2 * cM, 0);

  k_final<<<cB, 128, 0, stream>>>(fst, outF);
}

// Round 6
// 4973.639 us; speedup vs baseline: 2.0105x; 1.2732x over previous
//
#include <hip/hip_runtime.h>
#include <math.h>

constexpr int cB = 128;
constexpr int cC = 9;
constexpr int cT = 512;
constexpr int cM = 64;
constexpr int cDOB = 40;
constexpr int cDM = 360;
constexpr int cD = 376;       // d_model + d_pe
constexpr int cDH = 94;
constexpr int cNHID = 720;
constexpr float cEPS = 1e-5f;
constexpr float cPI = 3.14159265358979323846f;

typedef __attribute__((ext_vector_type(8))) short short8b;  // 8 bf16
typedef __attribute__((ext_vector_type(4))) float f32x4;

__device__ __forceinline__ short f2b(float f) {
  union { float f; unsigned u; } c; c.f = f;
  unsigned r = (c.u + 0x7fffu + ((c.u >> 16) & 1u)) >> 16;  // RNE
  return (short)r;
}
__device__ __forceinline__ float b2f(short h) {
  union { unsigned u; float f; } c; c.u = ((unsigned)(unsigned short)h) << 16;
  return c.f;
}

// ---------------- chirp kernel g = ifft(chirp) ----------------
__global__ void k_chirp(float2* __restrict__ g) {
  int d = threadIdx.x;  // 512 threads
  float re = 0.f, im = 0.f;
  for (int k = 0; k < cT; ++k) {
    int q = (k * k) & 2047;
    int p = (k * d) & 511;
    float th = cPI * ((float)p * (1.0f / 256.0f) - (float)q * (1.0f / 1024.0f));
    float s, c;
    sincosf(th, &s, &c);
    re += c; im += s;
  }
  g[d] = make_float2(re * (1.0f / 512.0f), im * (1.0f / 512.0f));
}

// ---------------- spectral branch ----------------
__global__ __launch_bounds__(512) void k_spectral(
    const float* __restrict__ x, const float* __restrict__ w1r,
    const float* __restrict__ w1i, const float2* __restrict__ g,
    float* __restrict__ outft, float* __restrict__ EF) {
  __shared__ float xc[cC][cT];
  __shared__ float2 gs[cT];
  __shared__ float2 xfr[cC][cM];
  int b = blockIdx.x, tid = threadIdx.x;
  for (int i = tid; i < cC * cT; i += 512)
    xc[i / cT][i % cT] = cosf(x[(size_t)b * cC * cT + i]);
  for (int i = tid; i < cT; i += 512) gs[i] = g[i];
  __syncthreads();
  for (int idx = tid; idx < cC * cM; idx += 512) {
    int c = idx / cM, m = idx % cM;
    float re = 0.f, im = 0.f;
    for (int t = 0; t < cT; ++t) {
      float xv = xc[c][t];
      float2 gv = gs[(m - t) & (cT - 1)];
      re += xv * gv.x; im += xv * gv.y;
    }
    xfr[c][m] = make_float2(re, im);
  }
  __syncthreads();
  for (int idx = tid; idx < cC * cM; idx += 512) {
    int o = idx / cM, m = idx % cM;
    float re = 0.f, im = 0.f;
    #pragma unroll
    for (int i = 0; i < cC; ++i) {
      float2 xv = xfr[i][m];
      float wr = w1r[(i * cC + o) * cM + m];
      float wi = w1i[(i * cC + o) * cM + m];
      re += xv.x * wr - xv.y * wi;
      im += xv.x * wi + xv.y * wr;
    }
    outft[(size_t)(b * cC + o) * cT + m] = re;   // real part only
    EF[(b * cC + o) * (2 * cM) + m] = sqrtf(re * re + im * im);
    EF[(b * cC + o) * (2 * cM) + cM + m] = atan2f(im, re);
  }
  for (int idx = tid; idx < cC * (cT - cM); idx += 512) {
    int o = idx / (cT - cM);
    int r = idx % (cT - cM);
    outft[(size_t)(b * cC + o) * cT + cM + r] = 0.f;
  }
}

// ---------------- conv1d C->1 over feature axis ----------------
__global__ void k_convef(const float* __restrict__ EF, const float* __restrict__ cw,
                         float* __restrict__ efp) {
  int i = blockIdx.x * blockDim.x + threadIdx.x;
  if (i >= cB * 2 * cM) return;
  int b = i / (2 * cM), f = i % (2 * cM);
  float acc = 0.f;
  #pragma unroll
  for (int c = 0; c < cC; ++c) {
    const float* row = EF + (b * cC + c) * (2 * cM);
    if (f > 0) acc += row[f - 1] * cw[c * 3 + 0];
    acc += row[f] * cw[c * 3 + 1];
    if (f < 2 * cM - 1) acc += row[f + 1] * cw[c * 3 + 2];
  }
  efp[i] = acc;
}

// ---------------- batchnorm over batch dim ----------------
__global__ __launch_bounds__(128) void k_bn(const float* __restrict__ in,
    const float* __restrict__ gam, const float* __restrict__ bet,
    float* __restrict__ dst, int F, int stride, int off, int reluAfter) {
  __shared__ float red[128];
  int f = blockIdx.x, bt = threadIdx.x;
  float v = in[(size_t)bt * F + f];
  red[bt] = v; __syncthreads();
  for (int s = 64; s > 0; s >>= 1) { if (bt < s) red[bt] += red[bt + s]; __syncthreads(); }
  float mean = red[0] * (1.0f / 128.0f);
  __syncthreads();
  float d = v - mean;
  red[bt] = d * d; __syncthreads();
  for (int s = 64; s > 0; s >>= 1) { if (bt < s) red[bt] += red[bt + s]; __syncthreads(); }
  float var = red[0] * (1.0f / 128.0f);
  float o = d * rsqrtf(var + cEPS) * gam[f] + bet[f];
  if (reluAfter) o = fmaxf(o, 0.f);
  dst[(size_t)bt * stride + off + f] = o;
}

// ---------------- raindrop branch -> z0 [Bc,T,D] ----------------
__global__ __launch_bounds__(256) void k_raindrop(const float* __restrict__ x,
    const float* __restrict__ Ru, const float* __restrict__ Wg1,
    const float* __restrict__ Wg2, float* __restrict__ Z, int bStart) {
  __shared__ float w1s[cDOB * cDOB], w2s[cDOB * cDOB], rus[cDM], tss[8];
  __shared__ float vsh[256][cDOB];
  int tid = threadIdx.x;
  for (int i = tid; i < cDOB * cDOB; i += 256) { w1s[i] = Wg1[i]; w2s[i] = Wg2[i]; }
  for (int i = tid; i < cDM; i += 256) rus[i] = Ru[i];
  if (tid < 8) tss[tid] = powf(100.0f, (float)tid * (1.0f / 7.0f));
  __syncthreads();
  int token0 = blockIdx.x * 256;
  int token = token0 + tid;
  int bl = token / cT, t = token % cT;
  int bg = bStart + bl;
  float s[cDOB];
  #pragma unroll
  for (int d = 0; d < cDOB; ++d) s[d] = 0.f;
  #pragma unroll
  for (int c = 0; c < cC; ++c) {
    float xv = x[((size_t)bg * cC + c) * cT + t];
    #pragma unroll
    for (int d = 0; d < cDOB; ++d) s[d] += fmaxf(xv * rus[c * cDOB + d], 0.f);
  }
  #pragma unroll
  for (int d = 0; d < cDOB; ++d) s[d] *= (1.0f / 9.0f);
  float u[cDOB];
  #pragma unroll
  for (int e = 0; e < cDOB; ++e) {
    float a = 0.f;
    #pragma unroll
    for (int d = 0; d < cDOB; ++d) a += s[d] * w1s[d * cDOB + e];
    u[e] = fmaxf(a, 0.f);
  }
  #pragma unroll
  for (int e = 0; e < cDOB; ++e) {
    float a = 0.f;
    #pragma unroll
    for (int d = 0; d < cDOB; ++d) a += u[d] * w2s[d * cDOB + e];
    vsh[tid][e] = fmaxf(a, 0.f);
  }
  __syncthreads();
  size_t zbase = (size_t)token0 * cD;
  for (int i = tid; i < 256 * cD; i += 256) {
    int tok = i / cD, col = i % cD;
    float val;
    if (col < cDM) {
      val = vsh[tok][col % cDOB];
    } else {
      int j = col - cDM;
      int tt = (token0 + tok) % cT;
      float st = (float)tt / tss[j & 7];
      val = (j < 8) ? sinf(st) : cosf(st);
    }
    Z[zbase + i] = val;
  }
}

// ---------------- transpose+convert: in[K][N] fp32 -> out[N][K] bf16 ----------------
__global__ __launch_bounds__(256) void k_cvtT(const float* __restrict__ in,
    short* __restrict__ out, int K, int N) {
  __shared__ float tile[32][33];
  int kb = blockIdx.x * 32, nb = blockIdx.y * 32;
  int tx = threadIdx.x & 31, ty = threadIdx.x >> 5;  // 32x8
  for (int i = ty; i < 32; i += 8) {
    int k = kb + i, n = nb + tx;
    tile[i][tx] = (k < K && n < N) ? in[(size_t)k * N + n] : 0.f;
  }
  __syncthreads();
  for (int i = ty; i < 32; i += 8) {
    int n = nb + i, k = kb + tx;
    if (n < N && k < K) out[(size_t)n * K + k] = f2b(tile[tx][i]);
  }
}

// ---------------- bf16 MFMA GEMM ----------------
__global__ __launch_bounds__(256) void k_gemm_mfma(
    const float* __restrict__ A, const short* __restrict__ Bt,
    const float* __restrict__ bias, float* __restrict__ Cm,
    int Mr, int Nc, int Kd, int relu) {
  __shared__ short As[64][40];
  __shared__ short Bs[64][40];
  int tid = threadIdx.x;
  int m0 = blockIdx.y * 64, n0 = blockIdx.x * 64;
  int w = tid >> 6, l = tid & 63;
  int wm = w >> 1, wn = w & 1;
  int lr = l & 15, lq = l >> 4;
  f32x4 acc[2][2];
  #pragma unroll
  for (int i = 0; i < 2; ++i)
    #pragma unroll
    for (int j = 0; j < 2; ++j)
      #pragma unroll
      for (int r = 0; r < 4; ++r) acc[i][j][r] = 0.f;
  int nK = (Kd + 31) >> 5;
  for (int ks = 0; ks < nK; ++ks) {
    int k0 = ks << 5;
    {
      int m = tid >> 2, kq = (tid & 3) << 3;
      int gm = m0 + m, gk = k0 + kq;
      float v[8];
      if (gm < Mr && gk + 7 < Kd) {
        float4 p0 = *(const float4*)(A + (size_t)gm * Kd + gk);
        float4 p1 = *(const float4*)(A + (size_t)gm * Kd + gk + 4);
        v[0]=p0.x; v[1]=p0.y; v[2]=p0.z; v[3]=p0.w;
        v[4]=p1.x; v[5]=p1.y; v[6]=p1.z; v[7]=p1.w;
      } else {
        #pragma unroll
        for (int j = 0; j < 8; ++j)
          v[j] = (gm < Mr && gk + j < Kd) ? A[(size_t)gm * Kd + gk + j] : 0.f;
      }
      short tmp[8];
      #pragma unroll
      for (int j = 0; j < 8; ++j) tmp[j] = f2b(v[j]);
      *(short8b*)&As[m][kq] = *(short8b*)tmp;
    }
    {
      int n = tid >> 2, kq = (tid & 3) << 3;
      int gn = n0 + n, gk = k0 + kq;
      short tmp[8];
      if (gn < Nc && gk + 7 < Kd) {
        *(short8b*)tmp = *(const short8b*)(Bt + (size_t)gn * Kd + gk);
      } else {
        #pragma unroll
        for (int j = 0; j < 8; ++j)
          tmp[j] = (gn < Nc && gk + j < Kd) ? Bt[(size_t)gn * Kd + gk + j] : (short)0;
      }
      *(short8b*)&Bs[n][kq] = *(short8b*)tmp;
    }
    __syncthreads();
    short8b af[2], bfr[2];
    #pragma unroll
    for (int f = 0; f < 2; ++f) {
      af[f]  = *(short8b*)&As[wm * 32 + f * 16 + lr][lq * 8];
      bfr[f] = *(short8b*)&Bs[wn * 32 + f * 16 + lr][lq * 8];
    }
    #pragma unroll
    for (int i = 0; i < 2; ++i)
      #pragma unroll
      for (int j = 0; j < 2; ++j)
        acc[i][j] = __builtin_amdgcn_mfma_f32_16x16x32_bf16(af[i], bfr[j], acc[i][j], 0, 0, 0);
    __syncthreads();
  }
  #pragma unroll
  for (int i = 0; i < 2; ++i)
    #pragma unroll
    for (int j = 0; j < 2; ++j) {
      int gn = n0 + wn * 32 + j * 16 + lr;
      if (gn >= Nc) continue;
      float bv = bias ? bias[gn] : 0.f;
      int gmb = m0 + wm * 32 + i * 16 + lq * 4;
      #pragma unroll
      for (int r = 0; r < 4; ++r) {
        int gm = gmb + r;
        if (gm >= Mr) continue;
        float vv = acc[i][j][r] + bv;
        if (relu) vv = fmaxf(vv, 0.f);
        Cm[(size_t)gm * Nc + gn] = vv;
      }
    }
}

// ---------------- fp32 tiled GEMM (final projection only) ----------------
__global__ __launch_bounds__(256) void k_gemm(const float* __restrict__ A,
    const float* __restrict__ Bm, const float* __restrict__ bias,
    float* __restrict__ Cm, int Mr, int Nc, int Kd, int relu) {
  __shared__ float As[16][68];
  __shared__ float Bs[16][68];
  int tid = threadIdx.x;
  int tx = tid & 15, ty = tid >> 4;
  int n0 = blockIdx.x * 64, m0 = blockIdx.y * 64;
  float acc[4][4] = {{0.f}};
  for (int k0 = 0; k0 < Kd; k0 += 16) {
    {
      int row = tid >> 2, kq = (tid & 3) << 2;
      int gm = m0 + row, gk = k0 + kq;
      float4 av = make_float4(0.f, 0.f, 0.f, 0.f);
      if (gm < Mr) {
        const float* ap = A + (size_t)gm * Kd + gk;
        if (gk + 3 < Kd) av = *(const float4*)ap;
        else {
          if (gk + 0 < Kd) av.x = ap[0];
          if (gk + 1 < Kd) av.y = ap[1];
          if (gk + 2 < Kd) av.z = ap[2];
        }
      }
      As[kq + 0][row] = av.x; As[kq + 1][row] = av.y;
      As[kq + 2][row] = av.z; As[kq + 3][row] = av.w;
    }
    {
      int kr = tid >> 4, nc = (tid & 15) << 2;
      int gk = k0 + kr, gn = n0 + nc;
      float4 bv = make_float4(0.f, 0.f, 0.f, 0.f);
      if (gk < Kd && gn < Nc) {
        const float* bp = Bm + (size_t)gk * Nc + gn;
        if (gn + 3 < Nc) bv = *(const float4*)bp;
        else {
          bv.x = bp[0];
          if (gn + 1 < Nc) bv.y = bp[1];
          if (gn + 2 < Nc) bv.z = bp[2];
        }
      }
      *(float4*)&Bs[kr][nc] = bv;
    }
    __syncthreads();
    #pragma unroll
    for (int k = 0; k < 16; ++k) {
      float4 a = *(const float4*)&As[k][ty << 2];
      float4 b = *(const float4*)&Bs[k][tx << 2];
      acc[0][0] += a.x * b.x; acc[0][1] += a.x * b.y; acc[0][2] += a.x * b.z; acc[0][3] += a.x * b.w;
      acc[1][0] += a.y * b.x; acc[1][1] += a.y * b.y; acc[1][2] += a.y * b.z; acc[1][3] += a.y * b.w;
      acc[2][0] += a.z * b.x; acc[2][1] += a.z * b.y; acc[2][2] += a.z * b.z; acc[2][3] += a.z * b.w;
      acc[3][0] += a.w * b.x; acc[3][1] += a.w * b.y; acc[3][2] += a.w * b.z; acc[3][3] += a.w * b.w;
    }
    __syncthreads();
  }
  #pragma unroll
  for (int i = 0; i < 4; ++i) {
    int gm = m0 + (ty << 2) + i;
    if (gm >= Mr) continue;
    #pragma unroll
    for (int j = 0; j < 4; ++j) {
      int gn = n0 + (tx << 2) + j;
      if (gn >= Nc) continue;
      float v = acc[i][j] + (bias ? bias[gn] : 0.f);
      if (relu) v = fmaxf(v, 0.f);
      Cm[(size_t)gm * Nc + gn] = v;
    }
  }
}

// ---------------- MFMA flash attention (hi/lo bf16 compensated) ----------------
// grid (qb=8, h=4, b), 256 threads = 4 waves x 16 q-rows.
// K staged LDS oct-layout [d-oct][tok][8]; Q frags in regs; V read from global;
// computes O^T = V^T * P^T so P re-reads stay in B-frag layout.
__global__ __launch_bounds__(256) void k_attn_mfma(const float* __restrict__ QKV,
    float* __restrict__ ATT) {
  __shared__ __align__(16) char raw[12288 * 2 + 4 * 16 * 68 * 4 + 4 * 16 * 4 * 2];
  short* kq_h = (short*)raw;                    // [12][64][8] bf16 hi
  short* kq_l = (short*)(raw + 12288);          // lo
  int tid = threadIdx.x;
  int w = tid >> 6, l = tid & 63;
  int lr = l & 15, lg = l >> 4;
  float* p_w  = (float*)(raw + 24576) + w * 16 * 68;          // [16][68] fp32
  float* fs_w = (float*)(raw + 24576 + 17408) + w * 16;       // fsc per q
  float* il_w = (float*)(raw + 24576 + 17408 + 256) + w * 16; // 1/l per q
  int qb = blockIdx.x, h = blockIdx.y, bl = blockIdx.z;
  size_t tokBase = (size_t)bl * cT;
  const float scale = 0.103142125f;   // 1/sqrt(94)

  // ---- stage helper target: gbase rows 0..63, cols h-head (94 wide, pad 96) ----
  const float* qbase = QKV + (tokBase + qb * 64) * 1128ull + h * cDH;
  // stage Q into kq
  for (int task = tid; task < 768; task += 256) {
    int oct = task >> 6, tok = task & 63;
    const float* src = qbase + (size_t)tok * 1128 + oct * 8;
    int nv = (oct == 11) ? 6 : 8;
    float v[8];
    #pragma unroll
    for (int i = 0; i < 8; i += 2) {
      if (i < nv) { float2 t = *(const float2*)(src + i); v[i] = t.x; v[i + 1] = t.y; }
      else { v[i] = 0.f; v[i + 1] = 0.f; }
    }
    short ht[8], lt[8];
    #pragma unroll
    for (int i = 0; i < 8; ++i) { ht[i] = f2b(v[i]); lt[i] = f2b(v[i] - b2f(ht[i])); }
    *(short8b*)&kq_h[(oct * 64 + tok) * 8] = *(short8b*)ht;
    *(short8b*)&kq_l[(oct * 64 + tok) * 8] = *(short8b*)lt;
  }
  __syncthreads();
  // each lane pulls its 3 Q A-frags (k-octets s*4+lg), rows w*16+lr
  short8b qh_s[3], ql_s[3];
  #pragma unroll
  for (int s = 0; s < 3; ++s) {
    int o = s * 4 + lg;
    qh_s[s] = *(short8b*)&kq_h[(o * 64 + w * 16 + lr) * 8];
    ql_s[s] = *(short8b*)&kq_l[(o * 64 + w * 16 + lr) * 8];
  }

  f32x4 of[6];
  #pragma unroll
  for (int f = 0; f < 6; ++f)
    #pragma unroll
    for (int r = 0; r < 4; ++r) of[f][r] = 0.f;
  float mrow[4], lrow[4];
  #pragma unroll
  for (int r = 0; r < 4; ++r) { mrow[r] = -1e30f; lrow[r] = 0.f; }

  for (int kt = 0; kt < 8; ++kt) {
    __syncthreads();   // kq free (prev reads done); also guards Q frag reads on kt=0
    const float* kbase = QKV + (tokBase + kt * 64) * 1128ull + cD + h * cDH;
    for (int task = tid; task < 768; task += 256) {
      int oct = task >> 6, tok = task & 63;
      const float* src = kbase + (size_t)tok * 1128 + oct * 8;
      int nv = (oct == 11) ? 6 : 8;
      float v[8];
      #pragma unroll
      for (int i = 0; i < 8; i += 2) {
        if (i < nv) { float2 t = *(const float2*)(src + i); v[i] = t.x; v[i + 1] = t.y; }
        else { v[i] = 0.f; v[i + 1] = 0.f; }
      }
      short ht[8], lt[8];
      #pragma unroll
      for (int i = 0; i < 8; ++i) { ht[i] = f2b(v[i]); lt[i] = f2b(v[i] - b2f(ht[i])); }
      *(short8b*)&kq_h[(oct * 64 + tok) * 8] = *(short8b*)ht;
      *(short8b*)&kq_l[(oct * 64 + tok) * 8] = *(short8b*)lt;
    }
    __syncthreads();
    // ---- QK^T: S[q=lg*4+r (+0)][k=j*16+lr], compensated ----
    f32x4 sf4[4];
    #pragma unroll
    for (int j = 0; j < 4; ++j)
      #pragma unroll
      for (int r = 0; r < 4; ++r) sf4[j][r] = 0.f;
    #pragma unroll
    for (int j = 0; j < 4; ++j) {
      #pragma unroll
      for (int s = 0; s < 3; ++s) {
        short8b bh = *(short8b*)&kq_h[((s * 4 + lg) * 64 + j * 16 + lr) * 8];
        short8b bl2 = *(short8b*)&kq_l[((s * 4 + lg) * 64 + j * 16 + lr) * 8];
        sf4[j] = __builtin_amdgcn_mfma_f32_16x16x32_bf16(qh_s[s], bh, sf4[j], 0, 0, 0);
        sf4[j] = __builtin_amdgcn_mfma_f32_16x16x32_bf16(ql_s[s], bh, sf4[j], 0, 0, 0);
        sf4[j] = __builtin_amdgcn_mfma_f32_16x16x32_bf16(qh_s[s], bl2, sf4[j], 0, 0, 0);
      }
    }
    // ---- online softmax over k (cols) ----
    float pm[4][4], fscv[4];
    #pragma unroll
    for (int r = 0; r < 4; ++r) {
      float s0 = sf4[0][r] * scale, s1 = sf4[1][r] * scale;
      float s2 = sf4[2][r] * scale, s3 = sf4[3][r] * scale;
      float mx = fmaxf(fmaxf(s0, s1), fmaxf(s2, s3));
      for (int off = 8; off > 0; off >>= 1) mx = fmaxf(mx, __shfl_xor(mx, off, 16));
      float mnew = fmaxf(mrow[r], mx);
      float fsc = __expf(mrow[r] - mnew);
      pm[0][r] = __expf(s0 - mnew); pm[1][r] = __expf(s1 - mnew);
      pm[2][r] = __expf(s2 - mnew); pm[3][r] = __expf(s3 - mnew);
      float ps = pm[0][r] + pm[1][r] + pm[2][r] + pm[3][r];
      for (int off = 8; off > 0; off >>= 1) ps += __shfl_xor(ps, off, 16);
      lrow[r] = lrow[r] * fsc + ps;
      mrow[r] = mnew;
      fscv[r] = fsc;
    }
    // write P (fp32) in natural [q][k] layout; fsc per q
    #pragma unroll
    for (int j = 0; j < 4; ++j)
      #pragma unroll
      for (int r = 0; r < 4; ++r)
        p_w[(lg * 4 + r) * 68 + j * 16 + lr] = pm[j][r];
    if (lr == 0) {
      #pragma unroll
      for (int r = 0; r < 4; ++r) fs_w[lg * 4 + r] = fscv[r];
    }
    __syncthreads();
    // rescale O^T (col q = lr)
    float fs = fs_w[lr];
    #pragma unroll
    for (int f = 0; f < 6; ++f)
      #pragma unroll
      for (int r = 0; r < 4; ++r) of[f][r] *= fs;
    // ---- PV: O^T += V^T * P^T (compensated) ----
    const float* vbase = QKV + (tokBase + kt * 64) * 1128ull + 2 * cD + h * cDH;
    #pragma unroll
    for (int s = 0; s < 2; ++s) {
      float4 pa = *(const float4*)&p_w[lr * 68 + s * 32 + lg * 8];
      float4 pb = *(const float4*)&p_w[lr * 68 + s * 32 + lg * 8 + 4];
      float pf[8] = {pa.x, pa.y, pa.z, pa.w, pb.x, pb.y, pb.z, pb.w};
      short pht[8], plt[8];
      #pragma unroll
      for (int i = 0; i < 8; ++i) { pht[i] = f2b(pf[i]); plt[i] = f2b(pf[i] - b2f(pht[i])); }
      short8b ph = *(short8b*)pht, pl = *(short8b*)plt;
      int tokoff = s * 32 + lg * 8;
      #pragma unroll
      for (int f = 0; f < 6; ++f) {
        int d = f * 16 + lr;
        float vv[8];
        if (d < cDH) {
          #pragma unroll
          for (int i = 0; i < 8; ++i) vv[i] = vbase[(size_t)(tokoff + i) * 1128 + d];
        } else {
          #pragma unroll
          for (int i = 0; i < 8; ++i) vv[i] = 0.f;
        }
        short vht[8], vlt[8];
        #pragma unroll
        for (int i = 0; i < 8; ++i) { vht[i] = f2b(vv[i]); vlt[i] = f2b(vv[i] - b2f(vht[i])); }
        short8b vh = *(short8b*)vht, vl = *(short8b*)vlt;
        of[f] = __builtin_amdgcn_mfma_f32_16x16x32_bf16(vh, ph, of[f], 0, 0, 0);
        of[f] = __builtin_amdgcn_mfma_f32_16x16x32_bf16(vl, ph, of[f], 0, 0, 0);
        of[f] = __builtin_amdgcn_mfma_f32_16x16x32_bf16(vh, pl, of[f], 0, 0, 0);
      }
    }
  }
  // ---- epilogue: O^T -> obuf[q][d] (reuse kq LDS), then coalesced write ----
  if (lr == 0) {
    #pragma unroll
    for (int r = 0; r < 4; ++r) il_w[lg * 4 + r] = 1.0f / lrow[r];
  }
  __syncthreads();   // all kq reads done; il visible
  float il = il_w[lr];
  float* obuf = (float*)raw;   // [64][98]
  #pragma unroll
  for (int f = 0; f < 6; ++f) {
    #pragma unroll
    for (int r = 0; r < 4; ++r) {
      int d = f * 16 + lg * 4 + r;
      if (d < cDH) obuf[(w * 16 + lr) * 98 + d] = of[f][r] * il;
    }
  }
  __syncthreads();
  for (int idx = tid; idx < 64 * cDH; idx += 256) {
    int q = idx / cDH, d = idx % cDH;
    ATT[(tokBase + qb * 64 + q) * (size_t)cD + h * cDH + d] = obuf[q * 98 + d];
  }
}

// ---------------- z = LN(z + y) over last dim D ----------------
__global__ __launch_bounds__(128) void k_addln(float* __restrict__ Z,
    const float* __restrict__ Y, const float* __restrict__ gam,
    const float* __restrict__ bet) {
  __shared__ float red[128];
  size_t base = (size_t)blockIdx.x * cD;
  int tid = threadIdx.x;
  float v[3];
  float sum = 0.f;
  #pragma unroll
  for (int i = 0; i < 3; ++i) {
    int c = tid + i * 128;
    float t = 0.f;
    if (c < cD) t = Z[base + c] + Y[base + c];
    v[i] = t; sum += t;
  }
  red[tid] = sum; __syncthreads();
  for (int s = 64; s > 0; s >>= 1) { if (tid < s) red[tid] += red[tid + s]; __syncthreads(); }
  float mean = red[0] / (float)cD;
  __syncthreads();
  float vs = 0.f;
  #pragma unroll
  for (int i = 0; i < 3; ++i) {
    int c = tid + i * 128;
    if (c < cD) { float d = v[i] - mean; vs += d * d; }
  }
  red[tid] = vs; __syncthreads();
  for (int s = 64; s > 0; s >>= 1) { if (tid < s) red[tid] += red[tid + s]; __syncthreads(); }
  float inv = rsqrtf(red[0] / (float)cD + cEPS);
  #pragma unroll
  for (int i = 0; i < 3; ++i) {
    int c = tid + i * 128;
    if (c < cD) Z[base + c] = (v[i] - mean) * inv * gam[c] + bet[c];
  }
}

// ---------------- et[b,d] = mean_t Z[b,t,d] ----------------
__global__ __launch_bounds__(384) void k_meant(const float* __restrict__ Z,
    float* __restrict__ et, int bStart) {
  int bl = blockIdx.x, d = threadIdx.x;
  if (d >= cD) return;
  float s = 0.f;
  for (int t = 0; t < cT; ++t) s += Z[((size_t)bl * cT + t) * cD + d];
  et[(size_t)(bStart + bl) * cD + d] = s * (1.0f / 512.0f);
}

// ---------------- final L2-normalize ----------------
__global__ __launch_bounds__(128) void k_final(const float* __restrict__ fst,
    float* __restrict__ out) {
  __shared__ float red[128];
  int b = blockIdx.x, tid = threadIdx.x;
  float v[5]; float ss = 0.f;
  #pragma unroll
  for (int i = 0; i < 5; ++i) {
    v[i] = fst[(size_t)b * 640 + tid + i * 128];
    ss += v[i] * v[i];
  }
  red[tid] = ss; __syncthreads();
  for (int s = 64; s > 0; s >>= 1) { if (tid < s) red[tid] += red[tid + s]; __syncthreads(); }
  float inv = 1.0f / fmaxf(sqrtf(red[0]), 1e-12f);
  #pragma unroll
  for (int i = 0; i < 5; ++i) out[(size_t)b * 640 + tid + i * 128] = v[i] * inv;
}

extern "C" void kernel_launch(void* const* d_in, const int* in_sizes, int n_in,
                              void* d_out, int out_size, void* d_ws, size_t ws_size,
                              hipStream_t stream) {
  (void)in_sizes; (void)n_in; (void)out_size;
  const float* x     = (const float*)d_in[0];
  const float* w1r   = (const float*)d_in[1];
  const float* w1i   = (const float*)d_in[2];
  const float* convw = (const float*)d_in[3];
  const float* bnfg  = (const float*)d_in[4];
  const float* bnfb  = (const float*)d_in[5];
  const float* Ru    = (const float*)d_in[6];
  const float* Wg1   = (const float*)d_in[7];
  const float* Wg2   = (const float*)d_in[8];
  const float* Wqkv  = (const float*)d_in[9];
  const float* bqkv  = (const float*)d_in[10];
  const float* Wo    = (const float*)d_in[11];
  const float* bo    = (const float*)d_in[12];
  const float* ln1g  = (const float*)d_in[13];
  const float* ln1b  = (const float*)d_in[14];
  const float* W1    = (const float*)d_in[15];
  const float* b1    = (const float*)d_in[16];
  const float* W2    = (const float*)d_in[17];
  const float* b2    = (const float*)d_in[18];
  const float* ln2g  = (const float*)d_in[19];
  const float* ln2b  = (const float*)d_in[20];
  const float* Wp    = (const float*)d_in[21];
  const float* bp    = (const float*)d_in[22];
  const float* bnpg  = (const float*)d_in[23];
  const float* bnpb  = (const float*)d_in[24];

  float* W = (float*)d_ws;
  size_t wsFloats = ws_size / 4;
  float* fst = W;                       //  81920
  float* et  = fst + 81920;             //  48128
  float* etp = et + 48128;              //  65536
  float2* g  = (float2*)(etp + 65536);  //   1024 floats
  float* EF  = (float*)g + 1024;        // 147456
  float* efp = EF + 147456;             //  16384
  short* bfw = (short*)(efp + 16384);
  const size_t bfwFloats = 1660416;
  const size_t fixedFloats = 81920 + 48128 + 65536 + 1024 + 147456 + 16384 + bfwFloats;

  const size_t oQKV = 0;
  const size_t oWO  = oQKV + (size_t)3 * 1128 * 376;
  const size_t oW1  = oWO  + (size_t)3 * 376 * 376;
  const size_t oW2  = oW1  + (size_t)3 * 720 * 376;

  float* outF  = (float*)d_out;
  float* outft = outF + cB * 640;

  if (wsFloats < fixedFloats) return;

  int Bc = 0;
  float* chunk = nullptr;
  for (int c = 128; c >= 1; c >>= 1) {
    size_t need = (size_t)c * cT * (cD + 1128 + cD);
    if (fixedFloats + need <= wsFloats) { Bc = c; chunk = W + fixedFloats; break; }
  }
  bool haveChunk = (Bc > 0);

  if (haveChunk) {
    for (int l = 0; l < 3; ++l) {
      k_cvtT<<<dim3(12, 36), 256, 0, stream>>>(Wqkv + (size_t)l * cD * 1128,
          bfw + oQKV + (size_t)l * 1128 * 376, cD, 1128);
      k_cvtT<<<dim3(12, 12), 256, 0, stream>>>(Wo + (size_t)l * cD * cD,
          bfw + oWO + (size_t)l * 376 * 376, cD, cD);
      k_cvtT<<<dim3(12, 23), 256, 0, stream>>>(W1 + (size_t)l * cD * cNHID,
          bfw + oW1 + (size_t)l * 720 * 376, cD, cNHID);
      k_cvtT<<<dim3(23, 12), 256, 0, stream>>>(W2 + (size_t)l * cNHID * cD,
          bfw + oW2 + (size_t)l * 376 * 720, cNHID, cD);
    }

    float* Zb   = chunk;
    float* QKVb = Zb + (size_t)Bc * cT * cD;
    float* ATTb = QKVb + (size_t)Bc * cT * 1128;
    for (int b0 = 0; b0 < cB; b0 += Bc) {
      int ntok = Bc * cT;
      k_raindrop<<<ntok / 256, 256, 0, stream>>>(x, Ru, Wg1, Wg2, Zb, b0);
      for (int l = 0; l < 3; ++l) {
        k_gemm_mfma<<<dim3(18, ntok / 64), 256, 0, stream>>>(
            Zb, bfw + oQKV + (size_t)l * 1128 * 376,
            bqkv + (size_t)l * 1128, QKVb, ntok, 1128, cD, 0);
        k_attn_mfma<<<dim3(8, 4, Bc), 256, 0, stream>>>(QKVb, ATTb);
        k_gemm_mfma<<<dim3(6, ntok / 64), 256, 0, stream>>>(
            ATTb, bfw + oWO + (size_t)l * 376 * 376,
            bo + (size_t)l * cD, QKVb, ntok, cD, cD, 0);
        k_addln<<<ntok, 128, 0, stream>>>(Zb, QKVb, ln1g + l * cD, ln1b + l * cD);
        k_gemm_mfma<<<dim3(12, ntok / 64), 256, 0, stream>>>(
            Zb, bfw + oW1 + (size_t)l * 720 * 376,
            b1 + (size_t)l * cNHID, QKVb, ntok, cNHID, cD, 1);
        k_gemm_mfma<<<dim3(6, ntok / 64), 256, 0, stream>>>(
            QKVb, bfw + oW2 + (size_t)l * 376 * 720,
            b2 + (size_t)l * cD, ATTb, ntok, cD, cNHID, 0);
        k_addln<<<ntok, 128, 0, stream>>>(Zb, ATTb, ln2g + l * cD, ln2b + l * cD);
      }
      k_meant<<<Bc, 384, 0, stream>>>(Zb, et, b0);
    }
    k_gemm<<<dim3(cT / 64, cB / 64), 256, 0, stream>>>(et, Wp, bp, etp, cB, cT, cD, 1);
  }

  k_chirp<<<1, 512, 0, stream>>>(g);
  k_spectral<<<cB, 512, 0, stream>>>(x, w1r, w1i, g, outft, EF);
  k_convef<<<(cB * 2 * cM + 255) / 256, 256, 0, stream>>>(EF, convw, efp);
  k_bn<<<2 * cM, 128, 0, stream>>>(efp, bnfg, bnfb, fst, 2 * cM, 640, 0, 1);

  if (haveChunk)
    k_bn<<<cT, 128, 0, stream>>>(etp, bnpg, bnpb, fst, cT, 640, 2 * cM, 0);

  k_final<<<cB, 128, 0, stream>>>(fst, outF);
}

// Round 7
// 4579.271 us; speedup vs baseline: 2.1837x; 1.0861x over previous
//
#include <hip/hip_runtime.h>
#include <math.h>

constexpr int cB = 128;
constexpr int cC = 9;
constexpr int cT = 512;
constexpr int cM = 64;
constexpr int cDOB = 40;
constexpr int cDM = 360;
constexpr int cD = 376;       // d_model + d_pe
constexpr int cDH = 94;
constexpr int cNHID = 720;
constexpr float cEPS = 1e-5f;
constexpr float cPI = 3.14159265358979323846f;

typedef __attribute__((ext_vector_type(8))) short short8b;  // 8 bf16
typedef __attribute__((ext_vector_type(4))) float f32x4;

__device__ __forceinline__ short f2b(float f) {
  union { float f; unsigned u; } c; c.f = f;
  unsigned r = (c.u + 0x7fffu + ((c.u >> 16) & 1u)) >> 16;  // RNE
  return (short)r;
}
__device__ __forceinline__ float b2f(short h) {
  union { unsigned u; float f; } c; c.u = ((unsigned)(unsigned short)h) << 16;
  return c.f;
}

// ---------------- chirp kernel g = ifft(chirp) ----------------
__global__ void k_chirp(float2* __restrict__ g) {
  int d = threadIdx.x;  // 512 threads
  float re = 0.f, im = 0.f;
  for (int k = 0; k < cT; ++k) {
    int q = (k * k) & 2047;
    int p = (k * d) & 511;
    float th = cPI * ((float)p * (1.0f / 256.0f) - (float)q * (1.0f / 1024.0f));
    float s, c;
    sincosf(th, &s, &c);
    re += c; im += s;
  }
  g[d] = make_float2(re * (1.0f / 512.0f), im * (1.0f / 512.0f));
}

// ---------------- spectral branch ----------------
__global__ __launch_bounds__(512) void k_spectral(
    const float* __restrict__ x, const float* __restrict__ w1r,
    const float* __restrict__ w1i, const float2* __restrict__ g,
    float* __restrict__ outft, float* __restrict__ EF) {
  __shared__ float xc[cC][cT];
  __shared__ float2 gs[cT];
  __shared__ float2 xfr[cC][cM];
  int b = blockIdx.x, tid = threadIdx.x;
  for (int i = tid; i < cC * cT; i += 512)
    xc[i / cT][i % cT] = cosf(x[(size_t)b * cC * cT + i]);
  for (int i = tid; i < cT; i += 512) gs[i] = g[i];
  __syncthreads();
  for (int idx = tid; idx < cC * cM; idx += 512) {
    int c = idx / cM, m = idx % cM;
    float re = 0.f, im = 0.f;
    for (int t = 0; t < cT; ++t) {
      float xv = xc[c][t];
      float2 gv = gs[(m - t) & (cT - 1)];
      re += xv * gv.x; im += xv * gv.y;
    }
    xfr[c][m] = make_float2(re, im);
  }
  __syncthreads();
  for (int idx = tid; idx < cC * cM; idx += 512) {
    int o = idx / cM, m = idx % cM;
    float re = 0.f, im = 0.f;
    #pragma unroll
    for (int i = 0; i < cC; ++i) {
      float2 xv = xfr[i][m];
      float wr = w1r[(i * cC + o) * cM + m];
      float wi = w1i[(i * cC + o) * cM + m];
      re += xv.x * wr - xv.y * wi;
      im += xv.x * wi + xv.y * wr;
    }
    outft[(size_t)(b * cC + o) * cT + m] = re;   // real part only
    EF[(b * cC + o) * (2 * cM) + m] = sqrtf(re * re + im * im);
    EF[(b * cC + o) * (2 * cM) + cM + m] = atan2f(im, re);
  }
  for (int idx = tid; idx < cC * (cT - cM); idx += 512) {
    int o = idx / (cT - cM);
    int r = idx % (cT - cM);
    outft[(size_t)(b * cC + o) * cT + cM + r] = 0.f;
  }
}

// ---------------- conv1d C->1 over feature axis ----------------
__global__ void k_convef(const float* __restrict__ EF, const float* __restrict__ cw,
                         float* __restrict__ efp) {
  int i = blockIdx.x * blockDim.x + threadIdx.x;
  if (i >= cB * 2 * cM) return;
  int b = i / (2 * cM), f = i % (2 * cM);
  float acc = 0.f;
  #pragma unroll
  for (int c = 0; c < cC; ++c) {
    const float* row = EF + (b * cC + c) * (2 * cM);
    if (f > 0) acc += row[f - 1] * cw[c * 3 + 0];
    acc += row[f] * cw[c * 3 + 1];
    if (f < 2 * cM - 1) acc += row[f + 1] * cw[c * 3 + 2];
  }
  efp[i] = acc;
}

// ---------------- batchnorm over batch dim ----------------
__global__ __launch_bounds__(128) void k_bn(const float* __restrict__ in,
    const float* __restrict__ gam, const float* __restrict__ bet,
    float* __restrict__ dst, int F, int stride, int off, int reluAfter) {
  __shared__ float red[128];
  int f = blockIdx.x, bt = threadIdx.x;
  float v = in[(size_t)bt * F + f];
  red[bt] = v; __syncthreads();
  for (int s = 64; s > 0; s >>= 1) { if (bt < s) red[bt] += red[bt + s]; __syncthreads(); }
  float mean = red[0] * (1.0f / 128.0f);
  __syncthreads();
  float d = v - mean;
  red[bt] = d * d; __syncthreads();
  for (int s = 64; s > 0; s >>= 1) { if (bt < s) red[bt] += red[bt + s]; __syncthreads(); }
  float var = red[0] * (1.0f / 128.0f);
  float o = d * rsqrtf(var + cEPS) * gam[f] + bet[f];
  if (reluAfter) o = fmaxf(o, 0.f);
  dst[(size_t)bt * stride + off + f] = o;
}

// ---------------- raindrop branch -> z0 [Bc,T,D] ----------------
__global__ __launch_bounds__(256) void k_raindrop(const float* __restrict__ x,
    const float* __restrict__ Ru, const float* __restrict__ Wg1,
    const float* __restrict__ Wg2, float* __restrict__ Z, int bStart) {
  __shared__ float w1s[cDOB * cDOB], w2s[cDOB * cDOB], rus[cDM], tss[8];
  __shared__ float vsh[256][cDOB];
  int tid = threadIdx.x;
  for (int i = tid; i < cDOB * cDOB; i += 256) { w1s[i] = Wg1[i]; w2s[i] = Wg2[i]; }
  for (int i = tid; i < cDM; i += 256) rus[i] = Ru[i];
  if (tid < 8) tss[tid] = powf(100.0f, (float)tid * (1.0f / 7.0f));
  __syncthreads();
  int token0 = blockIdx.x * 256;
  int token = token0 + tid;
  int bl = token / cT, t = token % cT;
  int bg = bStart + bl;
  float s[cDOB];
  #pragma unroll
  for (int d = 0; d < cDOB; ++d) s[d] = 0.f;
  #pragma unroll
  for (int c = 0; c < cC; ++c) {
    float xv = x[((size_t)bg * cC + c) * cT + t];
    #pragma unroll
    for (int d = 0; d < cDOB; ++d) s[d] += fmaxf(xv * rus[c * cDOB + d], 0.f);
  }
  #pragma unroll
  for (int d = 0; d < cDOB; ++d) s[d] *= (1.0f / 9.0f);
  float u[cDOB];
  #pragma unroll
  for (int e = 0; e < cDOB; ++e) {
    float a = 0.f;
    #pragma unroll
    for (int d = 0; d < cDOB; ++d) a += s[d] * w1s[d * cDOB + e];
    u[e] = fmaxf(a, 0.f);
  }
  #pragma unroll
  for (int e = 0; e < cDOB; ++e) {
    float a = 0.f;
    #pragma unroll
    for (int d = 0; d < cDOB; ++d) a += u[d] * w2s[d * cDOB + e];
    vsh[tid][e] = fmaxf(a, 0.f);
  }
  __syncthreads();
  size_t zbase = (size_t)token0 * cD;
  for (int i = tid; i < 256 * cD; i += 256) {
    int tok = i / cD, col = i % cD;
    float val;
    if (col < cDM) {
      val = vsh[tok][col % cDOB];
    } else {
      int j = col - cDM;
      int tt = (token0 + tok) % cT;
      float st = (float)tt / tss[j & 7];
      val = (j < 8) ? sinf(st) : cosf(st);
    }
    Z[zbase + i] = val;
  }
}

// ---------------- transpose+convert: in[K][N] fp32 -> out[N][K] bf16 ----------------
__global__ __launch_bounds__(256) void k_cvtT(const float* __restrict__ in,
    short* __restrict__ out, int K, int N) {
  __shared__ float tile[32][33];
  int kb = blockIdx.x * 32, nb = blockIdx.y * 32;
  int tx = threadIdx.x & 31, ty = threadIdx.x >> 5;  // 32x8
  for (int i = ty; i < 32; i += 8) {
    int k = kb + i, n = nb + tx;
    tile[i][tx] = (k < K && n < N) ? in[(size_t)k * N + n] : 0.f;
  }
  __syncthreads();
  for (int i = ty; i < 32; i += 8) {
    int n = nb + i, k = kb + tx;
    if (n < N && k < K) out[(size_t)n * K + k] = f2b(tile[tx][i]);
  }
}

// ---------------- bf16 MFMA GEMM, 128x128 tile, 4 waves (64x64 each, 4x4 frags) ----------------
// C[M,N] = A[M,K](f32) @ Bt[N,K](bf16)^T + bias. BK=32.
__global__ __launch_bounds__(256) void k_gemm_mfma2(
    const float* __restrict__ A, const short* __restrict__ Bt,
    const float* __restrict__ bias, float* __restrict__ Cm,
    int Mr, int Nc, int Kd, int relu) {
  __shared__ short As[128][40];   // [m][k] bf16, +8 pad
  __shared__ short Bs[128][40];   // [n][k] bf16
  int tid = threadIdx.x;
  int m0 = blockIdx.y * 128, n0 = blockIdx.x * 128;
  int w = tid >> 6, l = tid & 63;
  int wm = w >> 1, wn = w & 1;
  int lr = l & 15, lg = l >> 4;
  f32x4 acc[4][4];
  #pragma unroll
  for (int i = 0; i < 4; ++i)
    #pragma unroll
    for (int j = 0; j < 4; ++j)
      #pragma unroll
      for (int r = 0; r < 4; ++r) acc[i][j][r] = 0.f;
  int srow = tid >> 1, skq = (tid & 1) << 4;   // each thread: 1 row, 16 k
  int nK = (Kd + 31) >> 5;
  for (int ks = 0; ks < nK; ++ks) {
    int k0 = ks << 5;
    {   // stage A (fp32 -> bf16): row m0+srow, k k0+skq..+15  (Kd % 4 == 0)
      int gm = m0 + srow;
      int gk = k0 + skq;
      float v[16];
      const float* ap = A + (size_t)gm * Kd + gk;
      #pragma unroll
      for (int c = 0; c < 4; ++c) {
        if (gm < Mr && gk + c * 4 + 3 < Kd) {
          float4 t = *(const float4*)(ap + c * 4);
          v[c*4+0] = t.x; v[c*4+1] = t.y; v[c*4+2] = t.z; v[c*4+3] = t.w;
        } else {
          v[c*4+0] = 0.f; v[c*4+1] = 0.f; v[c*4+2] = 0.f; v[c*4+3] = 0.f;
        }
      }
      short tmp[16];
      #pragma unroll
      for (int j = 0; j < 16; ++j) tmp[j] = f2b(v[j]);
      *(short8b*)&As[srow][skq]     = *(short8b*)&tmp[0];
      *(short8b*)&As[srow][skq + 8] = *(short8b*)&tmp[8];
    }
    {   // stage B (bf16): row n0+srow, k k0+skq..+15  (Kd % 8 == 0)
      int gn = n0 + srow;
      int gk = k0 + skq;
      short tmp[16];
      const short* bp = Bt + (size_t)gn * Kd + gk;
      #pragma unroll
      for (int c = 0; c < 2; ++c) {
        if (gn < Nc && gk + c * 8 + 7 < Kd) {
          *(short8b*)&tmp[c * 8] = *(const short8b*)(bp + c * 8);
        } else {
          #pragma unroll
          for (int j = 0; j < 8; ++j) tmp[c * 8 + j] = (short)0;
        }
      }
      *(short8b*)&Bs[srow][skq]     = *(short8b*)&tmp[0];
      *(short8b*)&Bs[srow][skq + 8] = *(short8b*)&tmp[8];
    }
    __syncthreads();
    short8b af[4], bf[4];
    #pragma unroll
    for (int i = 0; i < 4; ++i)
      af[i] = *(short8b*)&As[wm * 64 + i * 16 + lr][lg * 8];
    #pragma unroll
    for (int j = 0; j < 4; ++j)
      bf[j] = *(short8b*)&Bs[wn * 64 + j * 16 + lr][lg * 8];
    #pragma unroll
    for (int i = 0; i < 4; ++i)
      #pragma unroll
      for (int j = 0; j < 4; ++j)
        acc[i][j] = __builtin_amdgcn_mfma_f32_16x16x32_bf16(af[i], bf[j], acc[i][j], 0, 0, 0);
    __syncthreads();
  }
  // epilogue: C/D layout col=lane&15, row=(lane>>4)*4+reg  [m89-verified]
  #pragma unroll
  for (int i = 0; i < 4; ++i)
    #pragma unroll
    for (int j = 0; j < 4; ++j) {
      int gn = n0 + wn * 64 + j * 16 + lr;
      if (gn >= Nc) continue;
      float bv = bias ? bias[gn] : 0.f;
      int gmb = m0 + wm * 64 + i * 16 + lg * 4;
      #pragma unroll
      for (int r = 0; r < 4; ++r) {
        int gm = gmb + r;
        if (gm >= Mr) continue;
        float vv = acc[i][j][r] + bv;
        if (relu) vv = fmaxf(vv, 0.f);
        Cm[(size_t)gm * Nc + gn] = vv;
      }
    }
}

// ---------------- fp32 tiled GEMM (final projection only) ----------------
__global__ __launch_bounds__(256) void k_gemm(const float* __restrict__ A,
    const float* __restrict__ Bm, const float* __restrict__ bias,
    float* __restrict__ Cm, int Mr, int Nc, int Kd, int relu) {
  __shared__ float As[16][68];
  __shared__ float Bs[16][68];
  int tid = threadIdx.x;
  int tx = tid & 15, ty = tid >> 4;
  int n0 = blockIdx.x * 64, m0 = blockIdx.y * 64;
  float acc[4][4] = {{0.f}};
  for (int k0 = 0; k0 < Kd; k0 += 16) {
    {
      int row = tid >> 2, kq = (tid & 3) << 2;
      int gm = m0 + row, gk = k0 + kq;
      float4 av = make_float4(0.f, 0.f, 0.f, 0.f);
      if (gm < Mr) {
        const float* ap = A + (size_t)gm * Kd + gk;
        if (gk + 3 < Kd) av = *(const float4*)ap;
        else {
          if (gk + 0 < Kd) av.x = ap[0];
          if (gk + 1 < Kd) av.y = ap[1];
          if (gk + 2 < Kd) av.z = ap[2];
        }
      }
      As[kq + 0][row] = av.x; As[kq + 1][row] = av.y;
      As[kq + 2][row] = av.z; As[kq + 3][row] = av.w;
    }
    {
      int kr = tid >> 4, nc = (tid & 15) << 2;
      int gk = k0 + kr, gn = n0 + nc;
      float4 bv = make_float4(0.f, 0.f, 0.f, 0.f);
      if (gk < Kd && gn < Nc) {
        const float* bp = Bm + (size_t)gk * Nc + gn;
        if (gn + 3 < Nc) bv = *(const float4*)bp;
        else {
          bv.x = bp[0];
          if (gn + 1 < Nc) bv.y = bp[1];
          if (gn + 2 < Nc) bv.z = bp[2];
        }
      }
      *(float4*)&Bs[kr][nc] = bv;
    }
    __syncthreads();
    #pragma unroll
    for (int k = 0; k < 16; ++k) {
      float4 a = *(const float4*)&As[k][ty << 2];
      float4 b = *(const float4*)&Bs[k][tx << 2];
      acc[0][0] += a.x * b.x; acc[0][1] += a.x * b.y; acc[0][2] += a.x * b.z; acc[0][3] += a.x * b.w;
      acc[1][0] += a.y * b.x; acc[1][1] += a.y * b.y; acc[1][2] += a.y * b.z; acc[1][3] += a.y * b.w;
      acc[2][0] += a.z * b.x; acc[2][1] += a.z * b.y; acc[2][2] += a.z * b.z; acc[2][3] += a.z * b.w;
      acc[3][0] += a.w * b.x; acc[3][1] += a.w * b.y; acc[3][2] += a.w * b.z; acc[3][3] += a.w * b.w;
    }
    __syncthreads();
  }
  #pragma unroll
  for (int i = 0; i < 4; ++i) {
    int gm = m0 + (ty << 2) + i;
    if (gm >= Mr) continue;
    #pragma unroll
    for (int j = 0; j < 4; ++j) {
      int gn = n0 + (tx << 2) + j;
      if (gn >= Nc) continue;
      float v = acc[i][j] + (bias ? bias[gn] : 0.f);
      if (relu) v = fmaxf(v, 0.f);
      Cm[(size_t)gm * Nc + gn] = v;
    }
  }
}

// ---------------- MFMA flash attention (hi/lo bf16 compensated) ----------------
__global__ __launch_bounds__(256) void k_attn_mfma(const float* __restrict__ QKV,
    float* __restrict__ ATT) {
  __shared__ __align__(16) char raw[12288 * 2 + 4 * 16 * 68 * 4 + 4 * 16 * 4 * 2];
  short* kq_h = (short*)raw;                    // [12][64][8] bf16 hi
  short* kq_l = (short*)(raw + 12288);          // lo
  int tid = threadIdx.x;
  int w = tid >> 6, l = tid & 63;
  int lr = l & 15, lg = l >> 4;
  float* p_w  = (float*)(raw + 24576) + w * 16 * 68;          // [16][68] fp32
  float* fs_w = (float*)(raw + 24576 + 17408) + w * 16;       // fsc per q
  float* il_w = (float*)(raw + 24576 + 17408 + 256) + w * 16; // 1/l per q
  int qb = blockIdx.x, h = blockIdx.y, bl = blockIdx.z;
  size_t tokBase = (size_t)bl * cT;
  const float scale = 0.103142125f;   // 1/sqrt(94)

  const float* qbase = QKV + (tokBase + qb * 64) * 1128ull + h * cDH;
  for (int task = tid; task < 768; task += 256) {
    int oct = task >> 6, tok = task & 63;
    const float* src = qbase + (size_t)tok * 1128 + oct * 8;
    int nv = (oct == 11) ? 6 : 8;
    float v[8];
    #pragma unroll
    for (int i = 0; i < 8; i += 2) {
      if (i < nv) { float2 t = *(const float2*)(src + i); v[i] = t.x; v[i + 1] = t.y; }
      else { v[i] = 0.f; v[i + 1] = 0.f; }
    }
    short ht[8], lt[8];
    #pragma unroll
    for (int i = 0; i < 8; ++i) { ht[i] = f2b(v[i]); lt[i] = f2b(v[i] - b2f(ht[i])); }
    *(short8b*)&kq_h[(oct * 64 + tok) * 8] = *(short8b*)ht;
    *(short8b*)&kq_l[(oct * 64 + tok) * 8] = *(short8b*)lt;
  }
  __syncthreads();
  short8b qh_s[3], ql_s[3];
  #pragma unroll
  for (int s = 0; s < 3; ++s) {
    int o = s * 4 + lg;
    qh_s[s] = *(short8b*)&kq_h[(o * 64 + w * 16 + lr) * 8];
    ql_s[s] = *(short8b*)&kq_l[(o * 64 + w * 16 + lr) * 8];
  }

  f32x4 of[6];
  #pragma unroll
  for (int f = 0; f < 6; ++f)
    #pragma unroll
    for (int r = 0; r < 4; ++r) of[f][r] = 0.f;
  float mrow[4], lrow[4];
  #pragma unroll
  for (int r = 0; r < 4; ++r) { mrow[r] = -1e30f; lrow[r] = 0.f; }

  for (int kt = 0; kt < 8; ++kt) {
    __syncthreads();
    const float* kbase = QKV + (tokBase + kt * 64) * 1128ull + cD + h * cDH;
    for (int task = tid; task < 768; task += 256) {
      int oct = task >> 6, tok = task & 63;
      const float* src = kbase + (size_t)tok * 1128 + oct * 8;
      int nv = (oct == 11) ? 6 : 8;
      float v[8];
      #pragma unroll
      for (int i = 0; i < 8; i += 2) {
        if (i < nv) { float2 t = *(const float2*)(src + i); v[i] = t.x; v[i + 1] = t.y; }
        else { v[i] = 0.f; v[i + 1] = 0.f; }
      }
      short ht[8], lt[8];
      #pragma unroll
      for (int i = 0; i < 8; ++i) { ht[i] = f2b(v[i]); lt[i] = f2b(v[i] - b2f(ht[i])); }
      *(short8b*)&kq_h[(oct * 64 + tok) * 8] = *(short8b*)ht;
      *(short8b*)&kq_l[(oct * 64 + tok) * 8] = *(short8b*)lt;
    }
    __syncthreads();
    f32x4 sf4[4];
    #pragma unroll
    for (int j = 0; j < 4; ++j)
      #pragma unroll
      for (int r = 0; r < 4; ++r) sf4[j][r] = 0.f;
    #pragma unroll
    for (int j = 0; j < 4; ++j) {
      #pragma unroll
      for (int s = 0; s < 3; ++s) {
        short8b bh = *(short8b*)&kq_h[((s * 4 + lg) * 64 + j * 16 + lr) * 8];
        short8b bl2 = *(short8b*)&kq_l[((s * 4 + lg) * 64 + j * 16 + lr) * 8];
        sf4[j] = __builtin_amdgcn_mfma_f32_16x16x32_bf16(qh_s[s], bh, sf4[j], 0, 0, 0);
        sf4[j] = __builtin_amdgcn_mfma_f32_16x16x32_bf16(ql_s[s], bh, sf4[j], 0, 0, 0);
        sf4[j] = __builtin_amdgcn_mfma_f32_16x16x32_bf16(qh_s[s], bl2, sf4[j], 0, 0, 0);
      }
    }
    float pm[4][4], fscv[4];
    #pragma unroll
    for (int r = 0; r < 4; ++r) {
      float s0 = sf4[0][r] * scale, s1 = sf4[1][r] * scale;
      float s2 = sf4[2][r] * scale, s3 = sf4[3][r] * scale;
      float mx = fmaxf(fmaxf(s0, s1), fmaxf(s2, s3));
      for (int off = 8; off > 0; off >>= 1) mx = fmaxf(mx, __shfl_xor(mx, off, 16));
      float mnew = fmaxf(mrow[r], mx);
      float fsc = __expf(mrow[r] - mnew);
      pm[0][r] = __expf(s0 - mnew); pm[1][r] = __expf(s1 - mnew);
      pm[2][r] = __expf(s2 - mnew); pm[3][r] = __expf(s3 - mnew);
      float ps = pm[0][r] + pm[1][r] + pm[2][r] + pm[3][r];
      for (int off = 8; off > 0; off >>= 1) ps += __shfl_xor(ps, off, 16);
      lrow[r] = lrow[r] * fsc + ps;
      mrow[r] = mnew;
      fscv[r] = fsc;
    }
    #pragma unroll
    for (int j = 0; j < 4; ++j)
      #pragma unroll
      for (int r = 0; r < 4; ++r)
        p_w[(lg * 4 + r) * 68 + j * 16 + lr] = pm[j][r];
    if (lr == 0) {
      #pragma unroll
      for (int r = 0; r < 4; ++r) fs_w[lg * 4 + r] = fscv[r];
    }
    __syncthreads();
    float fs = fs_w[lr];
    #pragma unroll
    for (int f = 0; f < 6; ++f)
      #pragma unroll
      for (int r = 0; r < 4; ++r) of[f][r] *= fs;
    const float* vbase = QKV + (tokBase + kt * 64) * 1128ull + 2 * cD + h * cDH;
    #pragma unroll
    for (int s = 0; s < 2; ++s) {
      float4 pa = *(const float4*)&p_w[lr * 68 + s * 32 + lg * 8];
      float4 pb = *(const float4*)&p_w[lr * 68 + s * 32 + lg * 8 + 4];
      float pf[8] = {pa.x, pa.y, pa.z, pa.w, pb.x, pb.y, pb.z, pb.w};
      short pht[8], plt[8];
      #pragma unroll
      for (int i = 0; i < 8; ++i) { pht[i] = f2b(pf[i]); plt[i] = f2b(pf[i] - b2f(pht[i])); }
      short8b ph = *(short8b*)pht, pl = *(short8b*)plt;
      int tokoff = s * 32 + lg * 8;
      #pragma unroll
      for (int f = 0; f < 6; ++f) {
        int d = f * 16 + lr;
        float vv[8];
        if (d < cDH) {
          #pragma unroll
          for (int i = 0; i < 8; ++i) vv[i] = vbase[(size_t)(tokoff + i) * 1128 + d];
        } else {
          #pragma unroll
          for (int i = 0; i < 8; ++i) vv[i] = 0.f;
        }
        short vht[8], vlt[8];
        #pragma unroll
        for (int i = 0; i < 8; ++i) { vht[i] = f2b(vv[i]); vlt[i] = f2b(vv[i] - b2f(vht[i])); }
        short8b vh = *(short8b*)vht, vl = *(short8b*)vlt;
        of[f] = __builtin_amdgcn_mfma_f32_16x16x32_bf16(vh, ph, of[f], 0, 0, 0);
        of[f] = __builtin_amdgcn_mfma_f32_16x16x32_bf16(vl, ph, of[f], 0, 0, 0);
        of[f] = __builtin_amdgcn_mfma_f32_16x16x32_bf16(vh, pl, of[f], 0, 0, 0);
      }
    }
  }
  if (lr == 0) {
    #pragma unroll
    for (int r = 0; r < 4; ++r) il_w[lg * 4 + r] = 1.0f / lrow[r];
  }
  __syncthreads();
  float il = il_w[lr];
  float* obuf = (float*)raw;   // [64][98]
  #pragma unroll
  for (int f = 0; f < 6; ++f) {
    #pragma unroll
    for (int r = 0; r < 4; ++r) {
      int d = f * 16 + lg * 4 + r;
      if (d < cDH) obuf[(w * 16 + lr) * 98 + d] = of[f][r] * il;
    }
  }
  __syncthreads();
  for (int idx = tid; idx < 64 * cDH; idx += 256) {
    int q = idx / cDH, d = idx % cDH;
    ATT[(tokBase + qb * 64 + q) * (size_t)cD + h * cDH + d] = obuf[q * 98 + d];
  }
}

// ---------------- z = LN(z + y) over last dim D ----------------
__global__ __launch_bounds__(128) void k_addln(float* __restrict__ Z,
    const float* __restrict__ Y, const float* __restrict__ gam,
    const float* __restrict__ bet) {
  __shared__ float red[128];
  size_t base = (size_t)blockIdx.x * cD;
  int tid = threadIdx.x;
  float v[3];
  float sum = 0.f;
  #pragma unroll
  for (int i = 0; i < 3; ++i) {
    int c = tid + i * 128;
    float t = 0.f;
    if (c < cD) t = Z[base + c] + Y[base + c];
    v[i] = t; sum += t;
  }
  red[tid] = sum; __syncthreads();
  for (int s = 64; s > 0; s >>= 1) { if (tid < s) red[tid] += red[tid + s]; __syncthreads(); }
  float mean = red[0] / (float)cD;
  __syncthreads();
  float vs = 0.f;
  #pragma unroll
  for (int i = 0; i < 3; ++i) {
    int c = tid + i * 128;
    if (c < cD) { float d = v[i] - mean; vs += d * d; }
  }
  red[tid] = vs; __syncthreads();
  for (int s = 64; s > 0; s >>= 1) { if (tid < s) red[tid] += red[tid + s]; __syncthreads(); }
  float inv = rsqrtf(red[0] / (float)cD + cEPS);
  #pragma unroll
  for (int i = 0; i < 3; ++i) {
    int c = tid + i * 128;
    if (c < cD) Z[base + c] = (v[i] - mean) * inv * gam[c] + bet[c];
  }
}

// ---------------- et[b,d] = mean_t Z[b,t,d] ----------------
__global__ __launch_bounds__(384) void k_meant(const float* __restrict__ Z,
    float* __restrict__ et, int bStart) {
  int bl = blockIdx.x, d = threadIdx.x;
  if (d >= cD) return;
  float s = 0.f;
  for (int t = 0; t < cT; ++t) s += Z[((size_t)bl * cT + t) * cD + d];
  et[(size_t)(bStart + bl) * cD + d] = s * (1.0f / 512.0f);
}

// ---------------- final L2-normalize ----------------
__global__ __launch_bounds__(128) void k_final(const float* __restrict__ fst,
    float* __restrict__ out) {
  __shared__ float red[128];
  int b = blockIdx.x, tid = threadIdx.x;
  float v[5]; float ss = 0.f;
  #pragma unroll
  for (int i = 0; i < 5; ++i) {
    v[i] = fst[(size_t)b * 640 + tid + i * 128];
    ss += v[i] * v[i];
  }
  red[tid] = ss; __syncthreads();
  for (int s = 64; s > 0; s >>= 1) { if (tid < s) red[tid] += red[tid + s]; __syncthreads(); }
  float inv = 1.0f / fmaxf(sqrtf(red[0]), 1e-12f);
  #pragma unroll
  for (int i = 0; i < 5; ++i) out[(size_t)b * 640 + tid + i * 128] = v[i] * inv;
}

extern "C" void kernel_launch(void* const* d_in, const int* in_sizes, int n_in,
                              void* d_out, int out_size, void* d_ws, size_t ws_size,
                              hipStream_t stream) {
  (void)in_sizes; (void)n_in; (void)out_size;
  const float* x     = (const float*)d_in[0];
  const float* w1r   = (const float*)d_in[1];
  const float* w1i   = (const float*)d_in[2];
  const float* convw = (const float*)d_in[3];
  const float* bnfg  = (const float*)d_in[4];
  const float* bnfb  = (const float*)d_in[5];
  const float* Ru    = (const float*)d_in[6];
  const float* Wg1   = (const float*)d_in[7];
  const float* Wg2   = (const float*)d_in[8];
  const float* Wqkv  = (const float*)d_in[9];
  const float* bqkv  = (const float*)d_in[10];
  const float* Wo    = (const float*)d_in[11];
  const float* bo    = (const float*)d_in[12];
  const float* ln1g  = (const float*)d_in[13];
  const float* ln1b  = (const float*)d_in[14];
  const float* W1    = (const float*)d_in[15];
  const float* b1    = (const float*)d_in[16];
  const float* W2    = (const float*)d_in[17];
  const float* b2    = (const float*)d_in[18];
  const float* ln2g  = (const float*)d_in[19];
  const float* ln2b  = (const float*)d_in[20];
  const float* Wp    = (const float*)d_in[21];
  const float* bp    = (const float*)d_in[22];
  const float* bnpg  = (const float*)d_in[23];
  const float* bnpb  = (const float*)d_in[24];

  float* W = (float*)d_ws;
  size_t wsFloats = ws_size / 4;
  float* fst = W;                       //  81920
  float* et  = fst + 81920;             //  48128
  float* etp = et + 48128;              //  65536
  float2* g  = (float2*)(etp + 65536);  //   1024 floats
  float* EF  = (float*)g + 1024;        // 147456
  float* efp = EF + 147456;             //  16384
  short* bfw = (short*)(efp + 16384);
  const size_t bfwFloats = 1660416;
  const size_t fixedFloats = 81920 + 48128 + 65536 + 1024 + 147456 + 16384 + bfwFloats;

  const size_t oQKV = 0;
  const size_t oWO  = oQKV + (size_t)3 * 1128 * 376;
  const size_t oW1  = oWO  + (size_t)3 * 376 * 376;
  const size_t oW2  = oW1  + (size_t)3 * 720 * 376;

  float* outF  = (float*)d_out;
  float* outft = outF + cB * 640;

  if (wsFloats < fixedFloats) return;

  int Bc = 0;
  float* chunk = nullptr;
  for (int c = 128; c >= 1; c >>= 1) {
    size_t need = (size_t)c * cT * (cD + 1128 + cD);
    if (fixedFloats + need <= wsFloats) { Bc = c; chunk = W + fixedFloats; break; }
  }
  bool haveChunk = (Bc > 0);

  if (haveChunk) {
    for (int l = 0; l < 3; ++l) {
      k_cvtT<<<dim3(12, 36), 256, 0, stream>>>(Wqkv + (size_t)l * cD * 1128,
          bfw + oQKV + (size_t)l * 1128 * 376, cD, 1128);
      k_cvtT<<<dim3(12, 12), 256, 0, stream>>>(Wo + (size_t)l * cD * cD,
          bfw + oWO + (size_t)l * 376 * 376, cD, cD);
      k_cvtT<<<dim3(12, 23), 256, 0, stream>>>(W1 + (size_t)l * cD * cNHID,
          bfw + oW1 + (size_t)l * 720 * 376, cD, cNHID);
      k_cvtT<<<dim3(23, 12), 256, 0, stream>>>(W2 + (size_t)l * cNHID * cD,
          bfw + oW2 + (size_t)l * 376 * 720, cNHID, cD);
    }

    float* Zb   = chunk;
    float* QKVb = Zb + (size_t)Bc * cT * cD;
    float* ATTb = QKVb + (size_t)Bc * cT * 1128;
    for (int b0 = 0; b0 < cB; b0 += Bc) {
      int ntok = Bc * cT;
      int mt = (ntok + 127) / 128;
      k_raindrop<<<ntok / 256, 256, 0, stream>>>(x, Ru, Wg1, Wg2, Zb, b0);
      for (int l = 0; l < 3; ++l) {
        k_gemm_mfma2<<<dim3(9, mt), 256, 0, stream>>>(
            Zb, bfw + oQKV + (size_t)l * 1128 * 376,
            bqkv + (size_t)l * 1128, QKVb, ntok, 1128, cD, 0);
        k_attn_mfma<<<dim3(8, 4, Bc), 256, 0, stream>>>(QKVb, ATTb);
        k_gemm_mfma2<<<dim3(3, mt), 256, 0, stream>>>(
            ATTb, bfw + oWO + (size_t)l * 376 * 376,
            bo + (size_t)l * cD, QKVb, ntok, cD, cD, 0);
        k_addln<<<ntok, 128, 0, stream>>>(Zb, QKVb, ln1g + l * cD, ln1b + l * cD);
        k_gemm_mfma2<<<dim3(6, mt), 256, 0, stream>>>(
            Zb, bfw + oW1 + (size_t)l * 720 * 376,
            b1 + (size_t)l * cNHID, QKVb, ntok, cNHID, cD, 1);
        k_gemm_mfma2<<<dim3(3, mt), 256, 0, stream>>>(
            QKVb, bfw + oW2 + (size_t)l * 376 * 720,
            b2 + (size_t)l * cD, ATTb, ntok, cD, cNHID, 0);
        k_addln<<<ntok, 128, 0, stream>>>(Zb, ATTb, ln2g + l * cD, ln2b + l * cD);
      }
      k_meant<<<Bc, 384, 0, stream>>>(Zb, et, b0);
    }
    k_gemm<<<dim3(cT / 64, cB / 64), 256, 0, stream>>>(et, Wp, bp, etp, cB, cT, cD, 1);
  }

  k_chirp<<<1, 512, 0, stream>>>(g);
  k_spectral<<<cB, 512, 0, stream>>>(x, w1r, w1i, g, outft, EF);
  k_convef<<<(cB * 2 * cM + 255) / 256, 256, 0, stream>>>(EF, convw, efp);
  k_bn<<<2 * cM, 128, 0, stream>>>(efp, bnfg, bnfb, fst, 2 * cM, 640, 0, 1);

  if (haveChunk)
    k_bn<<<cT, 128, 0, stream>>>(etp, bnpg, bnpb, fst, cT, 640, 2 * cM, 0);

  k_final<<<cB, 128, 0, stream>>>(fst, outF);
}